// Round 1
// baseline (793.298 us; speedup 1.0000x reference)
//
#include <hip/hip_runtime.h>
#include <math.h>

#define B_  8
#define N_  2048
#define D_  768
#define H_  12
#define HD_ 64
#define GB_ 1025
#define LB_ 9
#define NW_ 255

__device__ __forceinline__ float2 cmulf(float2 a, float2 b) {
  return make_float2(fmaf(a.x, b.x, -(a.y*b.y)), fmaf(a.x, b.y, a.y*b.x));
}
__device__ __forceinline__ float2 caddf(float2 a, float2 b){ return make_float2(a.x+b.x, a.y+b.y); }
__device__ __forceinline__ float2 csubf(float2 a, float2 b){ return make_float2(a.x-b.x, a.y-b.y); }

// ---------------------------------------------------------------- ctx mean
__global__ __launch_bounds__(256) void k_ctx(const float* __restrict__ x,
                                             float* __restrict__ ctx) {
  const int b = blockIdx.x;        // 8
  const int nc = blockIdx.y;       // 32 chunks of 64 n
  const int tid = threadIdx.x;
  const int n0 = nc * 64;
  for (int c = tid; c < D_; c += 256) {
    float s = 0.0f;
    #pragma unroll 4
    for (int n = 0; n < 64; ++n)
      s += x[((size_t)(b*N_ + n0 + n))*D_ + c];
    atomicAdd(&ctx[b*D_ + c], s);
  }
}

// ---------------------------------------------------------------- mlp layer 1 (gelu)
__global__ __launch_bounds__(256) void k_mlp1(const float* __restrict__ ctx,
                                              const float* __restrict__ w1g, const float* __restrict__ b1g,
                                              const float* __restrict__ w1l, const float* __restrict__ b1l,
                                              float* __restrict__ h1g, float* __restrict__ h1l) {
  __shared__ float cs[B_*D_];
  const int tid = threadIdx.x;
  for (int i = tid; i < B_*D_; i += 256) cs[i] = ctx[i] * (1.0f/(float)N_);  // fold mean
  __syncthreads();
  const bool isl = (blockIdx.y != 0);
  const float* w1 = isl ? w1l : w1g;
  const float* b1 = isl ? b1l : b1g;
  float*       h1 = isl ? h1l : h1g;
  const int i = blockIdx.x*256 + tid;   // < 768
  float acc[B_] = {};
  for (int k = 0; k < D_; ++k) {
    const float wv = w1[k*D_ + i];
    #pragma unroll
    for (int b = 0; b < B_; ++b) acc[b] = fmaf(cs[b*D_ + k], wv, acc[b]);
  }
  const float bias = b1[i];
  #pragma unroll
  for (int b = 0; b < B_; ++b) {
    const float v = acc[b] + bias;
    h1[b*D_ + i] = 0.5f * v * (1.0f + erff(v * 0.70710678118654752f));  // exact gelu
  }
}

// ---------------------------------------------------------------- mlp layer 2 (tanh)
__global__ __launch_bounds__(256) void k_mlp2(const float* __restrict__ h1g, const float* __restrict__ h1l,
                                              const float* __restrict__ w2g, const float* __restrict__ b2g,
                                              const float* __restrict__ w2l, const float* __restrict__ b2l,
                                              float* __restrict__ mg, float* __restrict__ ml) {
  __shared__ float hs[B_*D_];
  const int tid = threadIdx.x;
  const bool isg = (blockIdx.x < 49);   // 49 blocks global (12300), 1 block local (108)
  const float* h1 = isg ? h1g : h1l;
  for (int i = tid; i < B_*D_; i += 256) hs[i] = h1[i];
  __syncthreads();
  const int Jmax = isg ? (H_*GB_) : (H_*LB_);
  const int j = isg ? (blockIdx.x*256 + tid) : tid;
  if (j >= Jmax) return;
  const float* w2 = isg ? w2g : w2l;
  const float* b2 = isg ? b2g : b2l;
  float*       mo = isg ? mg  : ml;
  float acc[B_] = {};
  for (int i = 0; i < D_; ++i) {
    const float wv = w2[(size_t)i*Jmax + j];
    #pragma unroll
    for (int b = 0; b < B_; ++b) acc[b] = fmaf(hs[b*D_ + i], wv, acc[b]);
  }
  const float bias = b2[j];
  #pragma unroll
  for (int b = 0; b < B_; ++b) mo[(size_t)b*Jmax + j] = tanhf(acc[b] + bias);
}

// ---------------------------------------------------------------- spectral (global FFT + local windows)
__global__ __launch_bounds__(256) void k_spectral(
    const float* __restrict__ x,
    const float* __restrict__ bfg, const float* __restrict__ bfl,
    const float* __restrict__ mbg, const float* __restrict__ mbl,
    const float* __restrict__ mg,  const float* __restrict__ ml,
    const float* __restrict__ fw,  float* __restrict__ fused) {
  __shared__ float2 cb[N_];     // complex work buffer
  __shared__ float2 tw[1024];   // tw[m] = exp(-i*pi*m/1024)
  __shared__ float  xcol[N_];
  __shared__ float  lacc[N_];
  __shared__ float  ct16[16], st16[16], hw[16];

  const int tid = threadIdx.x;
  const int col = blockIdx.x;             // ((b*H + h)*HD + d) : d fastest for L2 locality
  const int d   = col & 63;
  const int bh  = col >> 6;
  const int h   = bh % H_;
  const int b   = bh / H_;
  const int c   = h*HD_ + d;

  for (int m = tid; m < 1024; m += 256) {
    float s_, c_;
    sincospif(-(float)m * (1.0f/1024.0f), &s_, &c_);
    tw[m] = make_float2(c_, s_);
  }
  if (tid < 16) {
    float s_, c_;
    sincospif((float)tid * 0.125f, &s_, &c_);   // angle 2*pi*t/16
    ct16[tid] = c_; st16[tid] = s_;
    hw[tid] = 0.5f*(1.0f - c_);                  // hann
  }
  for (int n = tid; n < N_; n += 256) {
    const float v = x[((size_t)(b*N_ + n))*D_ + c];
    xcol[n] = v;
    cb[n] = make_float2(v, 0.0f);
    lacc[n] = 0.0f;
  }
  __syncthreads();

  // ---- forward FFT: radix-2 DIF, stages paired (natural in -> bitrev out) ----
  #pragma unroll
  for (int sh = 10; sh >= 2; sh -= 2) {
    const int hspan = 1 << sh, hh = hspan >> 1;
    for (int t = tid; t < 512; t += 256) {
      const int p  = t & (hh-1);
      const int g  = t >> (sh-1);
      const int i0 = (g << (sh+1)) | p;
      float2 a = cb[i0], bb = cb[i0+hh], cc = cb[i0+hspan], dd = cb[i0+hspan+hh];
      const float2 w1  = tw[p << (10-sh)];
      const float2 w1b = tw[(p+hh) << (10-sh)];
      const float2 w2  = tw[p << (11-sh)];
      float2 ap = caddf(a, cc),  cp = cmulf(csubf(a, cc), w1);
      float2 bp = caddf(bb, dd), dp = cmulf(csubf(bb, dd), w1b);
      cb[i0]          = caddf(ap, bp);
      cb[i0+hh]       = cmulf(csubf(ap, bp), w2);
      cb[i0+hspan]    = caddf(cp, dp);
      cb[i0+hspan+hh] = cmulf(csubf(cp, dp), w2);
    }
    __syncthreads();
  }
  for (int t = tid; t < 1024; t += 256) {   // final half=1 stage (w=1)
    const int i0 = t << 1;
    float2 a = cb[i0], bb = cb[i0+1];
    cb[i0]   = caddf(a, bb);
    cb[i0+1] = csubf(a, bb);
  }
  __syncthreads();

  // ---- pointwise global filter + modrelu (operate in bit-reversed positions) ----
  const float fsc = 0.022097086912079610f;   // 1/sqrt(2048), ortho
  for (int k = tid; k <= 1024; k += 256) {
    const int ik = (int)(__brev((unsigned)k) >> 21);
    float2 v = cb[ik];
    const float filt = bfg[h*GB_ + k] + mg[(size_t)b*(H_*GB_) + h*GB_ + k];
    float gr = v.x * fsc * filt, gi = v.y * fsc * filt;
    const float a = sqrtf(gr*gr + gi*gi);
    const float f = fmaxf(a + mbg[h*GB_ + k], 0.0f) / fmaxf(a, 1e-6f);
    gr *= f; gi *= f;
    cb[ik] = make_float2(gr, gi);
    if (k >= 1 && k < 1024) {                 // Hermitian mirror
      const int im_ = (int)(__brev((unsigned)(2048 - k)) >> 21);
      cb[im_] = make_float2(gr, -gi);
    }
  }
  __syncthreads();

  // ---- inverse FFT: radix-2 DIT, stages paired (bitrev in -> natural out) ----
  for (int t = tid; t < 1024; t += 256) {   // first half=1 stage (w=1)
    const int i0 = t << 1;
    float2 a = cb[i0], bb = cb[i0+1];
    cb[i0]   = caddf(a, bb);
    cb[i0+1] = csubf(a, bb);
  }
  __syncthreads();
  #pragma unroll
  for (int sh = 2; sh <= 10; sh += 2) {
    const int hspan = 1 << sh, hh = hspan >> 1;
    for (int t = tid; t < 512; t += 256) {
      const int p  = t & (hh-1);
      const int g  = t >> (sh-1);
      const int i0 = (g << (sh+1)) | p;
      float2 a = cb[i0], bb = cb[i0+hh], cc = cb[i0+hspan], dd = cb[i0+hspan+hh];
      float2 w2  = tw[p << (11-sh)];       w2.y  = -w2.y;    // conj -> e^{+i}
      float2 w1  = tw[p << (10-sh)];       w1.y  = -w1.y;
      float2 w1b = tw[(p+hh) << (10-sh)];  w1b.y = -w1b.y;
      float2 t1 = cmulf(bb, w2);
      float2 ap = caddf(a, t1),  bp = csubf(a, t1);
      float2 t2 = cmulf(dd, w2);
      float2 cp = caddf(cc, t2), dp = csubf(cc, t2);
      float2 T = cmulf(cp, w1);
      float2 U = cmulf(dp, w1b);
      cb[i0]          = caddf(ap, T);
      cb[i0+hspan]    = csubf(ap, T);
      cb[i0+hh]       = caddf(bp, U);
      cb[i0+hspan+hh] = csubf(bp, U);
    }
    __syncthreads();
  }

  // ---- local windowed path: one thread per window ----
  float outw[16];
  const int j = tid;
  if (j < NW_) {
    float y[16];
    #pragma unroll
    for (int t = 0; t < 16; ++t) y[t] = xcol[j*8 + t] * hw[t];
    float cr[9], ci[9];
    #pragma unroll
    for (int l = 0; l <= 8; ++l) {
      float sr = 0.0f, si = 0.0f;
      #pragma unroll
      for (int t = 0; t < 16; ++t) {
        const int m = (l*t) & 15;
        sr = fmaf(y[t],  ct16[m], sr);
        si = fmaf(-y[t], st16[m], si);
      }
      sr *= 0.25f; si *= 0.25f;                 // ortho fwd 1/sqrt(16)
      const float filt = bfl[h*LB_ + l] + ml[(size_t)b*(H_*LB_) + h*LB_ + l];
      sr *= filt; si *= filt;
      const float a = sqrtf(sr*sr + si*si);
      const float f = fmaxf(a + mbl[h*LB_ + l], 0.0f) / fmaxf(a, 1e-6f);
      cr[l] = sr*f; ci[l] = si*f;
    }
    #pragma unroll
    for (int t = 0; t < 16; ++t) {
      float acc = cr[0] + cr[8]*ct16[(8*t) & 15];   // l=0 and l=8 terms are real
      #pragma unroll
      for (int l = 1; l <= 7; ++l) {
        const int m = (l*t) & 15;
        acc += 2.0f*(cr[l]*ct16[m] - ci[l]*st16[m]);
      }
      outw[t] = acc * 0.25f * hw[t];              // ortho inv * hann again
    }
  }
  __syncthreads();
  if (j < NW_ && !(j & 1)) {      // even windows: disjoint 16-wide spans
    #pragma unroll
    for (int t = 0; t < 16; ++t) lacc[j*8 + t] += outw[t];
  }
  __syncthreads();
  if (j < NW_ && (j & 1)) {       // odd windows
    #pragma unroll
    for (int t = 0; t < 16; ++t) lacc[j*8 + t] += outw[t];
  }
  __syncthreads();

  const float fw0 = fw[0], fw1 = fw[1];
  float* fcol = fused + (size_t)col * N_;
  for (int n = tid; n < N_; n += 256)
    fcol[n] = fw0 * (cb[n].x * fsc) + fw1 * lacc[n];
}

// ---------------------------------------------------------------- residual + LayerNorm
__global__ __launch_bounds__(256) void k_ln(const float* __restrict__ x,
                                            const float* __restrict__ fused,
                                            const float* __restrict__ gamma,
                                            const float* __restrict__ beta,
                                            float* __restrict__ out) {
  __shared__ float yt[16*769];
  __shared__ float mus[16], rsd[16];
  const int bi = blockIdx.x;           // b*128 + ntile
  const int b  = bi >> 7;
  const int n0 = (bi & 127) * 16;
  const int tid = threadIdx.x;

  for (int idx = tid; idx < 16*D_; idx += 256) {      // x load: coalesced
    const int nn = idx / D_, c = idx - nn*D_;
    yt[nn*769 + c] = x[((size_t)(b*N_ + n0 + nn))*D_ + c];
  }
  __syncthreads();
  for (int idx = tid; idx < 16*D_; idx += 256) {      // fused gather: 64B segments
    const int c = idx >> 4, nn = idx & 15;
    yt[nn*769 + c] += fused[((size_t)(b*D_ + c))*N_ + n0 + nn];
  }
  __syncthreads();
  const int nn = tid >> 4, cl = tid & 15;
  float s1 = 0.0f, s2 = 0.0f;
  for (int c = cl; c < D_; c += 16) {
    const float v = yt[nn*769 + c];
    s1 += v; s2 += v*v;
  }
  #pragma unroll
  for (int m = 8; m >= 1; m >>= 1) {
    s1 += __shfl_xor(s1, m, 16);
    s2 += __shfl_xor(s2, m, 16);
  }
  if (cl == 0) {
    const float mu  = s1 * (1.0f/(float)D_);
    const float var = s2 * (1.0f/(float)D_) - mu*mu;
    mus[nn] = mu;
    rsd[nn] = rsqrtf(var + 1e-5f);
  }
  __syncthreads();
  for (int idx = tid; idx < 16*D_; idx += 256) {
    const int nn2 = idx / D_, c = idx - nn2*D_;
    out[((size_t)(b*N_ + n0 + nn2))*D_ + c] =
        (yt[nn2*769 + c] - mus[nn2]) * rsd[nn2] * gamma[c] + beta[c];
  }
}

// ---------------------------------------------------------------- launch
extern "C" void kernel_launch(void* const* d_in, const int* in_sizes, int n_in,
                              void* d_out, int out_size, void* d_ws, size_t ws_size,
                              hipStream_t stream) {
  const float* x   = (const float*)d_in[0];
  const float* bfg = (const float*)d_in[1];
  const float* bfl = (const float*)d_in[2];
  const float* mbg = (const float*)d_in[3];
  const float* mbl = (const float*)d_in[4];
  const float* w1g = (const float*)d_in[5];
  const float* b1g = (const float*)d_in[6];
  const float* w2g = (const float*)d_in[7];
  const float* b2g = (const float*)d_in[8];
  const float* w1l = (const float*)d_in[9];
  const float* b1l = (const float*)d_in[10];
  const float* w2l = (const float*)d_in[11];
  const float* b2l = (const float*)d_in[12];
  const float* fw  = (const float*)d_in[13];
  const float* gam = (const float*)d_in[14];
  const float* bet = (const float*)d_in[15];
  float* out = (float*)d_out;

  float* ws    = (float*)d_ws;
  float* ctx   = ws;                 // 6144
  float* h1g   = ws + 6144;          // 6144
  float* h1l   = ws + 12288;         // 6144
  float* mg    = ws + 18432;         // 98400
  float* ml    = ws + 116832;        // 864
  float* fused = ws + 117696;        // 8*768*2048 = 12582912  (total ~48.5 MiB)

  hipMemsetAsync(ctx, 0, (size_t)B_*D_*sizeof(float), stream);
  k_ctx<<<dim3(B_, 32), 256, 0, stream>>>(x, ctx);
  k_mlp1<<<dim3(3, 2), 256, 0, stream>>>(ctx, w1g, b1g, w1l, b1l, h1g, h1l);
  k_mlp2<<<50, 256, 0, stream>>>(h1g, h1l, w2g, b2g, w2l, b2l, mg, ml);
  k_spectral<<<B_*H_*HD_, 256, 0, stream>>>(x, bfg, bfl, mbg, mbl, mg, ml, fw, fused);
  k_ln<<<B_*N_/16, 256, 0, stream>>>(x, fused, gam, bet, out);
}

// Round 2
// 523.541 us; speedup vs baseline: 1.5153x; 1.5153x over previous
//
#include <hip/hip_runtime.h>
#include <math.h>

#define B_  8
#define N_  2048
#define D_  768
#define H_  12
#define HD_ 64
#define GB_ 1025
#define LB_ 9
#define NW_ 255

__device__ __forceinline__ float2 cmulf(float2 a, float2 b) {
  return make_float2(fmaf(a.x, b.x, -(a.y*b.y)), fmaf(a.x, b.y, a.y*b.x));
}
__device__ __forceinline__ float2 caddf(float2 a, float2 b){ return make_float2(a.x+b.x, a.y+b.y); }
__device__ __forceinline__ float2 csubf(float2 a, float2 b){ return make_float2(a.x-b.x, a.y-b.y); }

// ---------------------------------------------------------------- ctx mean
__global__ __launch_bounds__(256) void k_ctx(const float* __restrict__ x,
                                             float* __restrict__ ctx) {
  const int b = blockIdx.x;        // 8
  const int nc = blockIdx.y;       // 32 chunks of 64 n
  const int tid = threadIdx.x;
  const int n0 = nc * 64;
  for (int c = tid; c < D_; c += 256) {
    float s = 0.0f;
    #pragma unroll 4
    for (int n = 0; n < 64; ++n)
      s += x[((size_t)(b*N_ + n0 + n))*D_ + c];
    atomicAdd(&ctx[b*D_ + c], s);
  }
}

// ---------------------------------------------------------------- mlp layer 1 (gelu)
__global__ __launch_bounds__(256) void k_mlp1(const float* __restrict__ ctx,
                                              const float* __restrict__ w1g, const float* __restrict__ b1g,
                                              const float* __restrict__ w1l, const float* __restrict__ b1l,
                                              float* __restrict__ h1g, float* __restrict__ h1l) {
  __shared__ float cs[B_*D_];
  const int tid = threadIdx.x;
  for (int i = tid; i < B_*D_; i += 256) cs[i] = ctx[i] * (1.0f/(float)N_);  // fold mean
  __syncthreads();
  const bool isl = (blockIdx.y != 0);
  const float* w1 = isl ? w1l : w1g;
  const float* b1 = isl ? b1l : b1g;
  float*       h1 = isl ? h1l : h1g;
  const int i = blockIdx.x*256 + tid;   // < 768
  float acc[B_] = {};
  for (int k = 0; k < D_; ++k) {
    const float wv = w1[k*D_ + i];
    #pragma unroll
    for (int b = 0; b < B_; ++b) acc[b] = fmaf(cs[b*D_ + k], wv, acc[b]);
  }
  const float bias = b1[i];
  #pragma unroll
  for (int b = 0; b < B_; ++b) {
    const float v = acc[b] + bias;
    h1[b*D_ + i] = 0.5f * v * (1.0f + erff(v * 0.70710678118654752f));  // exact gelu
  }
}

// ---------------------------------------------------------------- mlp layer 2 (tanh)
// 195 blocks: 193 global j-tiles of 64, 2 local j-tiles.
// Per block: slice = tid>>4 owns 48 i-rows; jg = tid&15 owns 4 j (float4).
// Reduce slices: shfl_xor(16/32) within wave, then padded-LDS across 4 waves.
__global__ __launch_bounds__(256) void k_mlp2(
    const float* __restrict__ h1g, const float* __restrict__ h1l,
    const float* __restrict__ w2g, const float* __restrict__ b2g,
    const float* __restrict__ w2l, const float* __restrict__ b2l,
    float* __restrict__ mg, float* __restrict__ ml) {
  __shared__ float hs[B_*D_];          // 24 KB
  __shared__ float red[4][16][33];     // padded: writer lanes conflict-free
  const int tid = threadIdx.x;
  const bool isg = (blockIdx.x < 193);
  const float* h1 = isg ? h1g : h1l;
  const float* w2 = isg ? w2g : w2l;
  const float* b2 = isg ? b2g : b2l;
  float*       mo = isg ? mg  : ml;
  const int Jmax = isg ? (H_*GB_) : (H_*LB_);
  const int j0   = isg ? (int)blockIdx.x*64 : ((int)blockIdx.x-193)*64;

  for (int i = tid; i < B_*D_; i += 256) hs[i] = h1[i];
  __syncthreads();

  const int jg    = tid & 15;
  const int slice = tid >> 4;
  const int j     = j0 + jg*4;
  float acc[8][4] = {};
  if (j < Jmax) {
    const float4* w24 = (const float4*)w2;
    const int jc   = j >> 2;
    const int rowq = Jmax >> 2;
    const int i0   = slice*48;
    #pragma unroll 4
    for (int ii = 0; ii < 48; ++ii) {
      const int i = i0 + ii;
      const float4 w = w24[(size_t)i*rowq + jc];
      #pragma unroll
      for (int b = 0; b < 8; ++b) {
        const float hv = hs[b*D_ + i];
        acc[b][0] = fmaf(hv, w.x, acc[b][0]);
        acc[b][1] = fmaf(hv, w.y, acc[b][1]);
        acc[b][2] = fmaf(hv, w.z, acc[b][2]);
        acc[b][3] = fmaf(hv, w.w, acc[b][3]);
      }
    }
  }
  // intra-wave: sum the 4 slices resident in this wave (lane bits 4,5)
  #pragma unroll
  for (int b = 0; b < 8; ++b) {
    #pragma unroll
    for (int q = 0; q < 4; ++q) {
      float v = acc[b][q];
      v += __shfl_xor(v, 16, 64);
      v += __shfl_xor(v, 32, 64);
      acc[b][q] = v;
    }
  }
  const int wv = tid >> 6;
  if ((tid & 63) < 16) {               // lane holds jg's wave-partial
    #pragma unroll
    for (int b = 0; b < 8; ++b)
      #pragma unroll
      for (int q = 0; q < 4; ++q)
        red[wv][jg][b*4+q] = acc[b][q];
  }
  __syncthreads();
  for (int s = tid; s < 512; s += 256) {   // 16 jg * 32 (b,q) outputs
    const int jg2 = s >> 5;
    const int v2  = s & 31;
    const int b   = v2 >> 2, q = v2 & 3;
    const int jo  = j0 + jg2*4 + q;
    if (jo < Jmax) {
      const float sum = red[0][jg2][v2] + red[1][jg2][v2]
                      + red[2][jg2][v2] + red[3][jg2][v2];
      mo[(size_t)b*Jmax + jo] = tanhf(sum + b2[jo]);
    }
  }
}

// ---------------------------------------------------------------- spectral (global FFT + local windows)
__global__ __launch_bounds__(256) void k_spectral(
    const float* __restrict__ x,
    const float* __restrict__ bfg, const float* __restrict__ bfl,
    const float* __restrict__ mbg, const float* __restrict__ mbl,
    const float* __restrict__ mg,  const float* __restrict__ ml,
    const float* __restrict__ fw,  float* __restrict__ fused) {
  __shared__ float2 cb[N_];     // complex work buffer
  __shared__ float2 tw[1024];   // tw[m] = exp(-i*pi*m/1024)
  __shared__ float  xcol[N_];
  __shared__ float  lacc[N_];
  __shared__ float  ct16[16], st16[16], hw[16];

  const int tid = threadIdx.x;
  const int col = blockIdx.x;             // ((b*H + h)*HD + d) : d fastest for L2 locality
  const int d   = col & 63;
  const int bh  = col >> 6;
  const int h   = bh % H_;
  const int b   = bh / H_;
  const int c   = h*HD_ + d;

  for (int m = tid; m < 1024; m += 256) {
    float s_, c_;
    sincospif(-(float)m * (1.0f/1024.0f), &s_, &c_);
    tw[m] = make_float2(c_, s_);
  }
  if (tid < 16) {
    float s_, c_;
    sincospif((float)tid * 0.125f, &s_, &c_);   // angle 2*pi*t/16
    ct16[tid] = c_; st16[tid] = s_;
    hw[tid] = 0.5f*(1.0f - c_);                  // hann
  }
  for (int n = tid; n < N_; n += 256) {
    const float v = x[((size_t)(b*N_ + n))*D_ + c];
    xcol[n] = v;
    cb[n] = make_float2(v, 0.0f);
    lacc[n] = 0.0f;
  }
  __syncthreads();

  // ---- forward FFT: radix-2 DIF, stages paired (natural in -> bitrev out) ----
  #pragma unroll
  for (int sh = 10; sh >= 2; sh -= 2) {
    const int hspan = 1 << sh, hh = hspan >> 1;
    for (int t = tid; t < 512; t += 256) {
      const int p  = t & (hh-1);
      const int g  = t >> (sh-1);
      const int i0 = (g << (sh+1)) | p;
      float2 a = cb[i0], bb = cb[i0+hh], cc = cb[i0+hspan], dd = cb[i0+hspan+hh];
      const float2 w1  = tw[p << (10-sh)];
      const float2 w1b = tw[(p+hh) << (10-sh)];
      const float2 w2  = tw[p << (11-sh)];
      float2 ap = caddf(a, cc),  cp = cmulf(csubf(a, cc), w1);
      float2 bp = caddf(bb, dd), dp = cmulf(csubf(bb, dd), w1b);
      cb[i0]          = caddf(ap, bp);
      cb[i0+hh]       = cmulf(csubf(ap, bp), w2);
      cb[i0+hspan]    = caddf(cp, dp);
      cb[i0+hspan+hh] = cmulf(csubf(cp, dp), w2);
    }
    __syncthreads();
  }
  for (int t = tid; t < 1024; t += 256) {   // final half=1 stage (w=1)
    const int i0 = t << 1;
    float2 a = cb[i0], bb = cb[i0+1];
    cb[i0]   = caddf(a, bb);
    cb[i0+1] = csubf(a, bb);
  }
  __syncthreads();

  // ---- pointwise global filter + modrelu (operate in bit-reversed positions) ----
  const float fsc = 0.022097086912079610f;   // 1/sqrt(2048), ortho
  for (int k = tid; k <= 1024; k += 256) {
    const int ik = (int)(__brev((unsigned)k) >> 21);
    float2 v = cb[ik];
    const float filt = bfg[h*GB_ + k] + mg[(size_t)b*(H_*GB_) + h*GB_ + k];
    float gr = v.x * fsc * filt, gi = v.y * fsc * filt;
    const float a = sqrtf(gr*gr + gi*gi);
    const float f = fmaxf(a + mbg[h*GB_ + k], 0.0f) / fmaxf(a, 1e-6f);
    gr *= f; gi *= f;
    cb[ik] = make_float2(gr, gi);
    if (k >= 1 && k < 1024) {                 // Hermitian mirror
      const int im_ = (int)(__brev((unsigned)(2048 - k)) >> 21);
      cb[im_] = make_float2(gr, -gi);
    }
  }
  __syncthreads();

  // ---- inverse FFT: radix-2 DIT, stages paired (bitrev in -> natural out) ----
  for (int t = tid; t < 1024; t += 256) {   // first half=1 stage (w=1)
    const int i0 = t << 1;
    float2 a = cb[i0], bb = cb[i0+1];
    cb[i0]   = caddf(a, bb);
    cb[i0+1] = csubf(a, bb);
  }
  __syncthreads();
  #pragma unroll
  for (int sh = 2; sh <= 10; sh += 2) {
    const int hspan = 1 << sh, hh = hspan >> 1;
    for (int t = tid; t < 512; t += 256) {
      const int p  = t & (hh-1);
      const int g  = t >> (sh-1);
      const int i0 = (g << (sh+1)) | p;
      float2 a = cb[i0], bb = cb[i0+hh], cc = cb[i0+hspan], dd = cb[i0+hspan+hh];
      float2 w2  = tw[p << (11-sh)];       w2.y  = -w2.y;    // conj -> e^{+i}
      float2 w1  = tw[p << (10-sh)];       w1.y  = -w1.y;
      float2 w1b = tw[(p+hh) << (10-sh)];  w1b.y = -w1b.y;
      float2 t1 = cmulf(bb, w2);
      float2 ap = caddf(a, t1),  bp = csubf(a, t1);
      float2 t2 = cmulf(dd, w2);
      float2 cp = caddf(cc, t2), dp = csubf(cc, t2);
      float2 T = cmulf(cp, w1);
      float2 U = cmulf(dp, w1b);
      cb[i0]          = caddf(ap, T);
      cb[i0+hspan]    = csubf(ap, T);
      cb[i0+hh]       = caddf(bp, U);
      cb[i0+hspan+hh] = csubf(bp, U);
    }
    __syncthreads();
  }

  // ---- local windowed path: one thread per window ----
  float outw[16];
  const int j = tid;
  if (j < NW_) {
    float y[16];
    #pragma unroll
    for (int t = 0; t < 16; ++t) y[t] = xcol[j*8 + t] * hw[t];
    float cr[9], ci[9];
    #pragma unroll
    for (int l = 0; l <= 8; ++l) {
      float sr = 0.0f, si = 0.0f;
      #pragma unroll
      for (int t = 0; t < 16; ++t) {
        const int m = (l*t) & 15;
        sr = fmaf(y[t],  ct16[m], sr);
        si = fmaf(-y[t], st16[m], si);
      }
      sr *= 0.25f; si *= 0.25f;                 // ortho fwd 1/sqrt(16)
      const float filt = bfl[h*LB_ + l] + ml[(size_t)b*(H_*LB_) + h*LB_ + l];
      sr *= filt; si *= filt;
      const float a = sqrtf(sr*sr + si*si);
      const float f = fmaxf(a + mbl[h*LB_ + l], 0.0f) / fmaxf(a, 1e-6f);
      cr[l] = sr*f; ci[l] = si*f;
    }
    #pragma unroll
    for (int t = 0; t < 16; ++t) {
      float acc = cr[0] + cr[8]*ct16[(8*t) & 15];   // l=0 and l=8 terms are real
      #pragma unroll
      for (int l = 1; l <= 7; ++l) {
        const int m = (l*t) & 15;
        acc += 2.0f*(cr[l]*ct16[m] - ci[l]*st16[m]);
      }
      outw[t] = acc * 0.25f * hw[t];              // ortho inv * hann again
    }
  }
  __syncthreads();
  if (j < NW_ && !(j & 1)) {      // even windows: disjoint 16-wide spans
    #pragma unroll
    for (int t = 0; t < 16; ++t) lacc[j*8 + t] += outw[t];
  }
  __syncthreads();
  if (j < NW_ && (j & 1)) {       // odd windows
    #pragma unroll
    for (int t = 0; t < 16; ++t) lacc[j*8 + t] += outw[t];
  }
  __syncthreads();

  const float fw0 = fw[0], fw1 = fw[1];
  float* fcol = fused + (size_t)col * N_;
  for (int n = tid; n < N_; n += 256)
    fcol[n] = fw0 * (cb[n].x * fsc) + fw1 * lacc[n];
}

// ---------------------------------------------------------------- residual + LayerNorm
__global__ __launch_bounds__(256) void k_ln(const float* __restrict__ x,
                                            const float* __restrict__ fused,
                                            const float* __restrict__ gamma,
                                            const float* __restrict__ beta,
                                            float* __restrict__ out) {
  __shared__ float yt[16*769];
  __shared__ float mus[16], rsd[16];
  const int bi = blockIdx.x;           // b*128 + ntile
  const int b  = bi >> 7;
  const int n0 = (bi & 127) * 16;
  const int tid = threadIdx.x;

  for (int idx = tid; idx < 16*D_; idx += 256) {      // x load: coalesced
    const int nn = idx / D_, c = idx - nn*D_;
    yt[nn*769 + c] = x[((size_t)(b*N_ + n0 + nn))*D_ + c];
  }
  __syncthreads();
  for (int idx = tid; idx < 16*D_; idx += 256) {      // fused gather: 64B segments
    const int c = idx >> 4, nn = idx & 15;
    yt[nn*769 + c] += fused[((size_t)(b*D_ + c))*N_ + n0 + nn];
  }
  __syncthreads();
  const int nn = tid >> 4, cl = tid & 15;
  float s1 = 0.0f, s2 = 0.0f;
  for (int c = cl; c < D_; c += 16) {
    const float v = yt[nn*769 + c];
    s1 += v; s2 += v*v;
  }
  #pragma unroll
  for (int m = 8; m >= 1; m >>= 1) {
    s1 += __shfl_xor(s1, m, 16);
    s2 += __shfl_xor(s2, m, 16);
  }
  if (cl == 0) {
    const float mu  = s1 * (1.0f/(float)D_);
    const float var = s2 * (1.0f/(float)D_) - mu*mu;
    mus[nn] = mu;
    rsd[nn] = rsqrtf(var + 1e-5f);
  }
  __syncthreads();
  for (int idx = tid; idx < 16*D_; idx += 256) {
    const int nn2 = idx / D_, c = idx - nn2*D_;
    out[((size_t)(b*N_ + n0 + nn2))*D_ + c] =
        (yt[nn2*769 + c] - mus[nn2]) * rsd[nn2] * gamma[c] + beta[c];
  }
}

// ---------------------------------------------------------------- launch
extern "C" void kernel_launch(void* const* d_in, const int* in_sizes, int n_in,
                              void* d_out, int out_size, void* d_ws, size_t ws_size,
                              hipStream_t stream) {
  const float* x   = (const float*)d_in[0];
  const float* bfg = (const float*)d_in[1];
  const float* bfl = (const float*)d_in[2];
  const float* mbg = (const float*)d_in[3];
  const float* mbl = (const float*)d_in[4];
  const float* w1g = (const float*)d_in[5];
  const float* b1g = (const float*)d_in[6];
  const float* w2g = (const float*)d_in[7];
  const float* b2g = (const float*)d_in[8];
  const float* w1l = (const float*)d_in[9];
  const float* b1l = (const float*)d_in[10];
  const float* w2l = (const float*)d_in[11];
  const float* b2l = (const float*)d_in[12];
  const float* fw  = (const float*)d_in[13];
  const float* gam = (const float*)d_in[14];
  const float* bet = (const float*)d_in[15];
  float* out = (float*)d_out;

  float* ws    = (float*)d_ws;
  float* ctx   = ws;                 // 6144
  float* h1g   = ws + 6144;          // 6144
  float* h1l   = ws + 12288;         // 6144
  float* mg    = ws + 18432;         // 98400
  float* ml    = ws + 116832;        // 864
  float* fused = ws + 117696;        // 8*768*2048 = 12582912  (total ~48.5 MiB)

  hipMemsetAsync(ctx, 0, (size_t)B_*D_*sizeof(float), stream);
  k_ctx<<<dim3(B_, 32), 256, 0, stream>>>(x, ctx);
  k_mlp1<<<dim3(3, 2), 256, 0, stream>>>(ctx, w1g, b1g, w1l, b1l, h1g, h1l);
  k_mlp2<<<195, 256, 0, stream>>>(h1g, h1l, w2g, b2g, w2l, b2l, mg, ml);
  k_spectral<<<B_*H_*HD_, 256, 0, stream>>>(x, bfg, bfl, mbg, mbl, mg, ml, fw, fused);
  k_ln<<<B_*N_/16, 256, 0, stream>>>(x, fused, gam, bet, out);
}

// Round 3
// 450.878 us; speedup vs baseline: 1.7595x; 1.1612x over previous
//
#include <hip/hip_runtime.h>
#include <math.h>

#define B_  8
#define N_  2048
#define D_  768
#define H_  12
#define HD_ 64
#define GB_ 1025
#define LB_ 9
#define NW_ 255

// LDS swizzles (bank-conflict breakers)
#define CBX(i) ((i) + ((i) >> 4))      // float2 array, pad every 16
#define XS(i)  ((i) + ((i) >> 3))      // float array, pad every 8

__device__ __forceinline__ float2 cmulf(float2 a, float2 b) {
  return make_float2(fmaf(a.x, b.x, -(a.y*b.y)), fmaf(a.x, b.y, a.y*b.x));
}
__device__ __forceinline__ float2 caddf(float2 a, float2 b){ return make_float2(a.x+b.x, a.y+b.y); }
__device__ __forceinline__ float2 csubf(float2 a, float2 b){ return make_float2(a.x-b.x, a.y-b.y); }

// ---------------------------------------------------------------- ctx mean
__global__ __launch_bounds__(256) void k_ctx(const float* __restrict__ x,
                                             float* __restrict__ ctx) {
  const int b = blockIdx.x;
  const int nc = blockIdx.y;
  const int tid = threadIdx.x;
  const int n0 = nc * 64;
  for (int c = tid; c < D_; c += 256) {
    float s = 0.0f;
    #pragma unroll 4
    for (int n = 0; n < 64; ++n)
      s += x[((size_t)(b*N_ + n0 + n))*D_ + c];
    atomicAdd(&ctx[b*D_ + c], s);
  }
}

// ---------------------------------------------------------------- mlp layer 1 (gelu)
__global__ __launch_bounds__(256) void k_mlp1(const float* __restrict__ ctx,
                                              const float* __restrict__ w1g, const float* __restrict__ b1g,
                                              const float* __restrict__ w1l, const float* __restrict__ b1l,
                                              float* __restrict__ h1g, float* __restrict__ h1l) {
  __shared__ float cs[B_*D_];
  const int tid = threadIdx.x;
  for (int i = tid; i < B_*D_; i += 256) cs[i] = ctx[i] * (1.0f/(float)N_);
  __syncthreads();
  const bool isl = (blockIdx.y != 0);
  const float* w1 = isl ? w1l : w1g;
  const float* b1 = isl ? b1l : b1g;
  float*       h1 = isl ? h1l : h1g;
  const int i = blockIdx.x*256 + tid;
  float acc[B_] = {};
  for (int k = 0; k < D_; ++k) {
    const float wv = w1[k*D_ + i];
    #pragma unroll
    for (int b = 0; b < B_; ++b) acc[b] = fmaf(cs[b*D_ + k], wv, acc[b]);
  }
  const float bias = b1[i];
  #pragma unroll
  for (int b = 0; b < B_; ++b) {
    const float v = acc[b] + bias;
    h1[b*D_ + i] = 0.5f * v * (1.0f + erff(v * 0.70710678118654752f));
  }
}

// ---------------------------------------------------------------- mlp layer 2 (tanh)
__global__ __launch_bounds__(256) void k_mlp2(
    const float* __restrict__ h1g, const float* __restrict__ h1l,
    const float* __restrict__ w2g, const float* __restrict__ b2g,
    const float* __restrict__ w2l, const float* __restrict__ b2l,
    float* __restrict__ mg, float* __restrict__ ml) {
  __shared__ float hs[B_*D_];
  __shared__ float red[4][16][33];
  const int tid = threadIdx.x;
  const bool isg = (blockIdx.x < 193);
  const float* h1 = isg ? h1g : h1l;
  const float* w2 = isg ? w2g : w2l;
  const float* b2 = isg ? b2g : b2l;
  float*       mo = isg ? mg  : ml;
  const int Jmax = isg ? (H_*GB_) : (H_*LB_);
  const int j0   = isg ? (int)blockIdx.x*64 : ((int)blockIdx.x-193)*64;

  for (int i = tid; i < B_*D_; i += 256) hs[i] = h1[i];
  __syncthreads();

  const int jg    = tid & 15;
  const int slice = tid >> 4;
  const int j     = j0 + jg*4;
  float acc[8][4] = {};
  if (j < Jmax) {
    const float4* w24 = (const float4*)w2;
    const int jc   = j >> 2;
    const int rowq = Jmax >> 2;
    const int i0   = slice*48;
    #pragma unroll 4
    for (int ii = 0; ii < 48; ++ii) {
      const int i = i0 + ii;
      const float4 w = w24[(size_t)i*rowq + jc];
      #pragma unroll
      for (int b = 0; b < 8; ++b) {
        const float hv = hs[b*D_ + i];
        acc[b][0] = fmaf(hv, w.x, acc[b][0]);
        acc[b][1] = fmaf(hv, w.y, acc[b][1]);
        acc[b][2] = fmaf(hv, w.z, acc[b][2]);
        acc[b][3] = fmaf(hv, w.w, acc[b][3]);
      }
    }
  }
  #pragma unroll
  for (int b = 0; b < 8; ++b) {
    #pragma unroll
    for (int q = 0; q < 4; ++q) {
      float v = acc[b][q];
      v += __shfl_xor(v, 16, 64);
      v += __shfl_xor(v, 32, 64);
      acc[b][q] = v;
    }
  }
  const int wv = tid >> 6;
  if ((tid & 63) < 16) {
    #pragma unroll
    for (int b = 0; b < 8; ++b)
      #pragma unroll
      for (int q = 0; q < 4; ++q)
        red[wv][jg][b*4+q] = acc[b][q];
  }
  __syncthreads();
  for (int s = tid; s < 512; s += 256) {
    const int jg2 = s >> 5;
    const int v2  = s & 31;
    const int b   = v2 >> 2, q = v2 & 3;
    const int jo  = j0 + jg2*4 + q;
    if (jo < Jmax) {
      const float sum = red[0][jg2][v2] + red[1][jg2][v2]
                      + red[2][jg2][v2] + red[3][jg2][v2];
      mo[(size_t)b*Jmax + jo] = tanhf(sum + b2[jo]);
    }
  }
}

// ---------------------------------------------------------------- spectral
// One block per COLUMN PAIR (d, d+1): two-for-one packed real FFT.
__global__ __launch_bounds__(256) void k_spectral(
    const float* __restrict__ x,
    const float* __restrict__ bfg, const float* __restrict__ bfl,
    const float* __restrict__ mbg, const float* __restrict__ mbl,
    const float* __restrict__ mg,  const float* __restrict__ ml,
    const float* __restrict__ fw,  float* __restrict__ fused) {
  __shared__ float2 cb[N_ + (N_>>4)];       // swizzled complex buffer
  __shared__ float2 tw[1024];               // tw[m] = exp(-i*pi*m/1024)
  __shared__ float  xc1[N_ + (N_>>3)], xc2[N_ + (N_>>3)];
  __shared__ float  la1[N_ + (N_>>3)], la2[N_ + (N_>>3)];
  __shared__ float  ct16[16], st16[16], hw[16];

  const int tid = threadIdx.x;
  const int blk = blockIdx.x;               // bh*32 + dpair
  const int dp  = blk & 31;
  const int bh  = blk >> 5;
  const int h   = bh % H_;
  const int b   = bh / H_;
  const int d   = dp * 2;
  const int c   = h*HD_ + d;
  const int col0 = bh*HD_ + d;              // row in fused (== b*D + c)

  for (int m = tid; m < 1024; m += 256) {
    float s_, c_;
    sincospif(-(float)m * (1.0f/1024.0f), &s_, &c_);
    tw[m] = make_float2(c_, s_);
  }
  if (tid < 16) {
    float s_, c_;
    sincospif((float)tid * 0.125f, &s_, &c_);
    ct16[tid] = c_; st16[tid] = s_;
    hw[tid] = 0.5f*(1.0f - c_);
  }
  for (int n = tid; n < N_ + (N_>>3); n += 256) { la1[n] = 0.0f; la2[n] = 0.0f; }
  for (int n = tid; n < N_; n += 256) {
    const float2 v = *(const float2*)&x[((size_t)(b*N_ + n))*D_ + c];
    xc1[XS(n)] = v.x; xc2[XS(n)] = v.y;
    cb[CBX(n)] = v;                          // z = x_d + i*x_{d+1}
  }
  __syncthreads();

  // ---- forward FFT: radix-2 DIF, stages paired (natural in -> bitrev out) ----
  #pragma unroll
  for (int sh = 10; sh >= 2; sh -= 2) {
    const int hspan = 1 << sh, hh = hspan >> 1;
    for (int t = tid; t < 512; t += 256) {
      const int p  = t & (hh-1);
      const int g  = t >> (sh-1);
      const int i0 = (g << (sh+1)) | p;
      float2 a = cb[CBX(i0)], bb = cb[CBX(i0+hh)], cc = cb[CBX(i0+hspan)], dd = cb[CBX(i0+hspan+hh)];
      const float2 w1  = tw[p << (10-sh)];
      const float2 w1b = tw[(p+hh) << (10-sh)];
      const float2 w2  = tw[p << (11-sh)];
      float2 ap = caddf(a, cc),  cp = cmulf(csubf(a, cc), w1);
      float2 bp = caddf(bb, dd), dp2 = cmulf(csubf(bb, dd), w1b);
      cb[CBX(i0)]          = caddf(ap, bp);
      cb[CBX(i0+hh)]       = cmulf(csubf(ap, bp), w2);
      cb[CBX(i0+hspan)]    = caddf(cp, dp2);
      cb[CBX(i0+hspan+hh)] = cmulf(csubf(cp, dp2), w2);
    }
    __syncthreads();
  }
  for (int t = tid; t < 1024; t += 256) {
    const int i0 = t << 1;
    float2 a = cb[CBX(i0)], bb = cb[CBX(i0+1)];
    cb[CBX(i0)]   = caddf(a, bb);
    cb[CBX(i0+1)] = csubf(a, bb);
  }
  __syncthreads();

  // ---- separate packed spectra, filter+modrelu both, repack (bitrev domain) ----
  const float fsc = 0.022097086912079610f;   // 1/sqrt(2048)
  {
    const float* mgp = mg + (size_t)b*(H_*GB_) + h*GB_;
    const float* bfp = bfg + h*GB_;
    const float* mbp = mbg + h*GB_;
    for (int k = tid; k < 1024; k += 256) {
      if (k == 0) {
        // DC (k=0) at bitrev 0, Nyquist (k=1024) at bitrev 1 — both spectra real there
        float2 Z0 = cb[CBX(0)], Zn = cb[CBX(1)];
        float g1 = Z0.x * fsc, g2 = Z0.y * fsc;
        {
          const float filt = bfp[0] + mgp[0], bias = mbp[0];
          g1 *= filt; g2 *= filt;
          float a1 = fabsf(g1); g1 *= fmaxf(a1 + bias, 0.0f) / fmaxf(a1, 1e-6f);
          float a2 = fabsf(g2); g2 *= fmaxf(a2 + bias, 0.0f) / fmaxf(a2, 1e-6f);
        }
        cb[CBX(0)] = make_float2(g1, g2);
        float n1 = Zn.x * fsc, n2 = Zn.y * fsc;
        {
          const float filt = bfp[1024] + mgp[1024], bias = mbp[1024];
          n1 *= filt; n2 *= filt;
          float a1 = fabsf(n1); n1 *= fmaxf(a1 + bias, 0.0f) / fmaxf(a1, 1e-6f);
          float a2 = fabsf(n2); n2 *= fmaxf(a2 + bias, 0.0f) / fmaxf(a2, 1e-6f);
        }
        cb[CBX(1)] = make_float2(n1, n2);
      } else {
        const int ik  = (int)(__brev((unsigned)k) >> 21);
        const int imk = (int)(__brev((unsigned)(2048 - k)) >> 21);
        const float2 Za = cb[CBX(ik)], Zb = cb[CBX(imk)];
        // F1 = (Za + conj(Zb))/2 ; F2 = -i(Za - conj(Zb))/2 ; then *fsc
        const float hs_ = 0.5f * fsc;
        float f1r = (Za.x + Zb.x) * hs_, f1i = (Za.y - Zb.y) * hs_;
        float f2r = (Za.y + Zb.y) * hs_, f2i = (Zb.x - Za.x) * hs_;
        const float filt = bfp[k] + mgp[k], bias = mbp[k];
        f1r *= filt; f1i *= filt; f2r *= filt; f2i *= filt;
        const float a1 = sqrtf(f1r*f1r + f1i*f1i);
        const float s1 = fmaxf(a1 + bias, 0.0f) / fmaxf(a1, 1e-6f);
        f1r *= s1; f1i *= s1;
        const float a2 = sqrtf(f2r*f2r + f2i*f2i);
        const float s2 = fmaxf(a2 + bias, 0.0f) / fmaxf(a2, 1e-6f);
        f2r *= s2; f2i *= s2;
        // W[k] = G1 + i G2 ; W[N-k] = conj(G1) + i conj(G2)
        cb[CBX(ik)]  = make_float2(f1r - f2i, f1i + f2r);
        cb[CBX(imk)] = make_float2(f1r + f2i, f2r - f1i);
      }
    }
  }
  __syncthreads();

  // ---- inverse FFT: radix-2 DIT (bitrev in -> natural out) ----
  for (int t = tid; t < 1024; t += 256) {
    const int i0 = t << 1;
    float2 a = cb[CBX(i0)], bb = cb[CBX(i0+1)];
    cb[CBX(i0)]   = caddf(a, bb);
    cb[CBX(i0+1)] = csubf(a, bb);
  }
  __syncthreads();
  #pragma unroll
  for (int sh = 2; sh <= 10; sh += 2) {
    const int hspan = 1 << sh, hh = hspan >> 1;
    for (int t = tid; t < 512; t += 256) {
      const int p  = t & (hh-1);
      const int g  = t >> (sh-1);
      const int i0 = (g << (sh+1)) | p;
      float2 a = cb[CBX(i0)], bb = cb[CBX(i0+hh)], cc = cb[CBX(i0+hspan)], dd = cb[CBX(i0+hspan+hh)];
      float2 w2  = tw[p << (11-sh)];       w2.y  = -w2.y;
      float2 w1  = tw[p << (10-sh)];       w1.y  = -w1.y;
      float2 w1b = tw[(p+hh) << (10-sh)];  w1b.y = -w1b.y;
      float2 t1 = cmulf(bb, w2);
      float2 ap = caddf(a, t1),  bp = csubf(a, t1);
      float2 t2 = cmulf(dd, w2);
      float2 cp = caddf(cc, t2), dp2 = csubf(cc, t2);
      float2 T = cmulf(cp, w1);
      float2 U = cmulf(dp2, w1b);
      cb[CBX(i0)]          = caddf(ap, T);
      cb[CBX(i0+hspan)]    = csubf(ap, T);
      cb[CBX(i0+hh)]       = caddf(bp, U);
      cb[CBX(i0+hspan+hh)] = csubf(bp, U);
    }
    __syncthreads();
  }

  // ---- local windowed path: per column, one thread per window ----
  const float* blp = bfl + h*LB_;
  const float* mlp = ml + (size_t)b*(H_*LB_) + h*LB_;
  const float* mbl_p = mbl + h*LB_;
  #pragma unroll
  for (int cc = 0; cc < 2; ++cc) {
    const float* xs = cc ? xc2 : xc1;
    float*       la = cc ? la2 : la1;
    float outw[16];
    const int j = tid;
    if (j < NW_) {
      float y[16];
      #pragma unroll
      for (int t = 0; t < 16; ++t) y[t] = xs[XS(j*8 + t)] * hw[t];
      float cr[9], ci[9];
      #pragma unroll
      for (int l = 0; l <= 8; ++l) {
        float sr = 0.0f, si = 0.0f;
        #pragma unroll
        for (int t = 0; t < 16; ++t) {
          const int m = (l*t) & 15;
          sr = fmaf(y[t],  ct16[m], sr);
          si = fmaf(-y[t], st16[m], si);
        }
        sr *= 0.25f; si *= 0.25f;
        const float filt = blp[l] + mlp[l];
        sr *= filt; si *= filt;
        const float a = sqrtf(sr*sr + si*si);
        const float f = fmaxf(a + mbl_p[l], 0.0f) / fmaxf(a, 1e-6f);
        cr[l] = sr*f; ci[l] = si*f;
      }
      #pragma unroll
      for (int t = 0; t < 16; ++t) {
        float acc = cr[0] + cr[8]*ct16[(8*t) & 15];
        #pragma unroll
        for (int l = 1; l <= 7; ++l) {
          const int m = (l*t) & 15;
          acc += 2.0f*(cr[l]*ct16[m] - ci[l]*st16[m]);
        }
        outw[t] = acc * 0.25f * hw[t];
      }
    }
    __syncthreads();
    if (j < NW_ && !(j & 1)) {
      #pragma unroll
      for (int t = 0; t < 16; ++t) la[XS(j*8 + t)] += outw[t];
    }
    __syncthreads();
    if (j < NW_ && (j & 1)) {
      #pragma unroll
      for (int t = 0; t < 16; ++t) la[XS(j*8 + t)] += outw[t];
    }
    __syncthreads();
  }

  const float fw0 = fw[0], fw1 = fw[1];
  float* f0 = fused + (size_t)col0 * N_;
  float* f1 = f0 + N_;
  for (int n = tid; n < N_; n += 256) {
    const float2 v = cb[CBX(n)];
    f0[n] = fw0 * (v.x * fsc) + fw1 * la1[XS(n)];
    f1[n] = fw0 * (v.y * fsc) + fw1 * la2[XS(n)];
  }
}

// ---------------------------------------------------------------- residual + LayerNorm
__global__ __launch_bounds__(256) void k_ln(const float* __restrict__ x,
                                            const float* __restrict__ fused,
                                            const float* __restrict__ gamma,
                                            const float* __restrict__ beta,
                                            float* __restrict__ out) {
  __shared__ float yt[16*772];
  __shared__ float mus[16], rsd[16];
  const int bi = blockIdx.x;
  const int b  = bi >> 7;
  const int n0 = (bi & 127) * 16;
  const int tid = threadIdx.x;

  // x load: fully-coalesced float4
  {
    const float4* x4 = (const float4*)(x + ((size_t)(b*N_ + n0))*D_);
    for (int i = tid; i < 16*D_/4; i += 256) {      // 3072 float4
      const int nn = i / 192, r = i - nn*192;
      const float4 v = x4[i];
      float* yp = &yt[nn*772 + r*4];
      yp[0] = v.x; yp[1] = v.y; yp[2] = v.z; yp[3] = v.w;
    }
  }
  __syncthreads();
  // fused gather: float4 along n (64B contiguous per c-row)
  {
    const float4* fu4 = (const float4*)fused;
    for (int i = tid; i < 16*D_/4; i += 256) {
      const int cc = i >> 2, q = (i & 3) * 4;       // cc<768, q in {0,4,8,12}
      const float4 g = fu4[(((size_t)(b*D_ + cc))*N_ + n0)/4 + (i & 3)];
      yt[(q+0)*772 + cc] += g.x;
      yt[(q+1)*772 + cc] += g.y;
      yt[(q+2)*772 + cc] += g.z;
      yt[(q+3)*772 + cc] += g.w;
    }
  }
  __syncthreads();
  const int nn = tid >> 4, cl = tid & 15;
  float s1 = 0.0f, s2 = 0.0f;
  for (int c = cl; c < D_; c += 16) {
    const float v = yt[nn*772 + c];
    s1 += v; s2 += v*v;
  }
  #pragma unroll
  for (int m = 8; m >= 1; m >>= 1) {
    s1 += __shfl_xor(s1, m, 16);
    s2 += __shfl_xor(s2, m, 16);
  }
  if (cl == 0) {
    const float mu  = s1 * (1.0f/(float)D_);
    const float var = s2 * (1.0f/(float)D_) - mu*mu;
    mus[nn] = mu;
    rsd[nn] = rsqrtf(var + 1e-5f);
  }
  __syncthreads();
  {
    float4* o4 = (float4*)(out + ((size_t)(b*N_ + n0))*D_);
    const float4* g4 = (const float4*)gamma;
    const float4* be4 = (const float4*)beta;
    for (int i = tid; i < 16*D_/4; i += 256) {
      const int nn2 = i / 192, r = i - nn2*192;
      const float mu = mus[nn2], rs = rsd[nn2];
      const float4 gm = g4[r], bt = be4[r];
      const float* yp = &yt[nn2*772 + r*4];
      float4 o;
      o.x = (yp[0] - mu) * rs * gm.x + bt.x;
      o.y = (yp[1] - mu) * rs * gm.y + bt.y;
      o.z = (yp[2] - mu) * rs * gm.z + bt.z;
      o.w = (yp[3] - mu) * rs * gm.w + bt.w;
      o4[i] = o;
    }
  }
}

// ---------------------------------------------------------------- launch
extern "C" void kernel_launch(void* const* d_in, const int* in_sizes, int n_in,
                              void* d_out, int out_size, void* d_ws, size_t ws_size,
                              hipStream_t stream) {
  const float* x   = (const float*)d_in[0];
  const float* bfg = (const float*)d_in[1];
  const float* bfl = (const float*)d_in[2];
  const float* mbg = (const float*)d_in[3];
  const float* mbl = (const float*)d_in[4];
  const float* w1g = (const float*)d_in[5];
  const float* b1g = (const float*)d_in[6];
  const float* w2g = (const float*)d_in[7];
  const float* b2g = (const float*)d_in[8];
  const float* w1l = (const float*)d_in[9];
  const float* b1l = (const float*)d_in[10];
  const float* w2l = (const float*)d_in[11];
  const float* b2l = (const float*)d_in[12];
  const float* fw  = (const float*)d_in[13];
  const float* gam = (const float*)d_in[14];
  const float* bet = (const float*)d_in[15];
  float* out = (float*)d_out;

  float* ws    = (float*)d_ws;
  float* ctx   = ws;                 // 6144
  float* h1g   = ws + 6144;
  float* h1l   = ws + 12288;
  float* mg    = ws + 18432;         // 98400
  float* ml    = ws + 116832;        // 864
  float* fused = ws + 117696;        // 8*768*2048

  hipMemsetAsync(ctx, 0, (size_t)B_*D_*sizeof(float), stream);
  k_ctx<<<dim3(B_, 32), 256, 0, stream>>>(x, ctx);
  k_mlp1<<<dim3(3, 2), 256, 0, stream>>>(ctx, w1g, b1g, w1l, b1l, h1g, h1l);
  k_mlp2<<<195, 256, 0, stream>>>(h1g, h1l, w2g, b2g, w2l, b2l, mg, ml);
  k_spectral<<<B_*H_*32, 256, 0, stream>>>(x, bfg, bfl, mbg, mbl, mg, ml, fw, fused);
  k_ln<<<B_*N_/16, 256, 0, stream>>>(x, fused, gam, bet, out);
}

// Round 4
// 375.650 us; speedup vs baseline: 2.1118x; 1.2003x over previous
//
#include <hip/hip_runtime.h>
#include <math.h>

#define B_  8
#define N_  2048
#define D_  768
#define H_  12
#define HD_ 64
#define GB_ 1025
#define LB_ 9
#define NW_ 255

// LDS swizzles (bank-conflict breakers)
#define CBX(i) ((i) + ((i) >> 4))      // float2 array, pad every 16
#define XS(i)  ((i) + ((i) >> 3))      // float array, pad every 8

__device__ __forceinline__ float2 cmulf(float2 a, float2 b) {
  return make_float2(fmaf(a.x, b.x, -(a.y*b.y)), fmaf(a.x, b.y, a.y*b.x));
}
__device__ __forceinline__ float2 caddf(float2 a, float2 b){ return make_float2(a.x+b.x, a.y+b.y); }
__device__ __forceinline__ float2 csubf(float2 a, float2 b){ return make_float2(a.x-b.x, a.y-b.y); }

// ---------------------------------------------------------------- ctx mean
__global__ __launch_bounds__(256) void k_ctx(const float* __restrict__ x,
                                             float* __restrict__ ctx) {
  const int b = blockIdx.x;
  const int nc = blockIdx.y;
  const int tid = threadIdx.x;
  const int n0 = nc * 64;
  for (int c = tid; c < D_; c += 256) {
    float s = 0.0f;
    #pragma unroll 4
    for (int n = 0; n < 64; ++n)
      s += x[((size_t)(b*N_ + n0 + n))*D_ + c];
    atomicAdd(&ctx[b*D_ + c], s);
  }
}

// ---------------------------------------------------------------- mlp layer 1 (gelu)
// mlp2-style tiling: 24 blocks (12 j-tiles x {global,local}), 64-col tiles,
// 16 i-slices of 48 rows, float4 weight loads, shuffle+LDS reduce.
__global__ __launch_bounds__(256) void k_mlp1(
    const float* __restrict__ ctx,
    const float* __restrict__ w1g, const float* __restrict__ b1g,
    const float* __restrict__ w1l, const float* __restrict__ b1l,
    float* __restrict__ h1g, float* __restrict__ h1l) {
  __shared__ float hs[B_*D_];
  __shared__ float red[4][16][33];
  const int tid = threadIdx.x;
  const bool isl = (blockIdx.y != 0);
  const float* w1 = isl ? w1l : w1g;
  const float* b1 = isl ? b1l : b1g;
  float*       h1 = isl ? h1l : h1g;
  const int j0 = (int)blockIdx.x * 64;

  for (int i = tid; i < B_*D_; i += 256) hs[i] = ctx[i] * (1.0f/(float)N_);
  __syncthreads();

  const int jg    = tid & 15;
  const int slice = tid >> 4;
  const int j     = j0 + jg*4;
  float acc[8][4] = {};
  {
    const float4* w14 = (const float4*)w1;
    const int jc = j >> 2;
    const int i0 = slice*48;
    #pragma unroll 4
    for (int ii = 0; ii < 48; ++ii) {
      const int i = i0 + ii;
      const float4 w = w14[(size_t)i*192 + jc];
      #pragma unroll
      for (int b = 0; b < 8; ++b) {
        const float hv = hs[b*D_ + i];
        acc[b][0] = fmaf(hv, w.x, acc[b][0]);
        acc[b][1] = fmaf(hv, w.y, acc[b][1]);
        acc[b][2] = fmaf(hv, w.z, acc[b][2]);
        acc[b][3] = fmaf(hv, w.w, acc[b][3]);
      }
    }
  }
  #pragma unroll
  for (int b = 0; b < 8; ++b) {
    #pragma unroll
    for (int q = 0; q < 4; ++q) {
      float v = acc[b][q];
      v += __shfl_xor(v, 16, 64);
      v += __shfl_xor(v, 32, 64);
      acc[b][q] = v;
    }
  }
  const int wv = tid >> 6;
  if ((tid & 63) < 16) {
    #pragma unroll
    for (int b = 0; b < 8; ++b)
      #pragma unroll
      for (int q = 0; q < 4; ++q)
        red[wv][jg][b*4+q] = acc[b][q];
  }
  __syncthreads();
  for (int s = tid; s < 512; s += 256) {
    const int jg2 = s >> 5;
    const int v2  = s & 31;
    const int b   = v2 >> 2, q = v2 & 3;
    const int jo  = j0 + jg2*4 + q;
    const float sum = red[0][jg2][v2] + red[1][jg2][v2]
                    + red[2][jg2][v2] + red[3][jg2][v2];
    const float v = sum + b1[jo];
    h1[(size_t)b*D_ + jo] = 0.5f * v * (1.0f + erff(v * 0.70710678118654752f));
  }
}

// ---------------------------------------------------------------- mlp layer 2 (tanh)
__global__ __launch_bounds__(256) void k_mlp2(
    const float* __restrict__ h1g, const float* __restrict__ h1l,
    const float* __restrict__ w2g, const float* __restrict__ b2g,
    const float* __restrict__ w2l, const float* __restrict__ b2l,
    float* __restrict__ mg, float* __restrict__ ml) {
  __shared__ float hs[B_*D_];
  __shared__ float red[4][16][33];
  const int tid = threadIdx.x;
  const bool isg = (blockIdx.x < 193);
  const float* h1 = isg ? h1g : h1l;
  const float* w2 = isg ? w2g : w2l;
  const float* b2 = isg ? b2g : b2l;
  float*       mo = isg ? mg  : ml;
  const int Jmax = isg ? (H_*GB_) : (H_*LB_);
  const int j0   = isg ? (int)blockIdx.x*64 : ((int)blockIdx.x-193)*64;

  for (int i = tid; i < B_*D_; i += 256) hs[i] = h1[i];
  __syncthreads();

  const int jg    = tid & 15;
  const int slice = tid >> 4;
  const int j     = j0 + jg*4;
  float acc[8][4] = {};
  if (j < Jmax) {
    const float4* w24 = (const float4*)w2;
    const int jc   = j >> 2;
    const int rowq = Jmax >> 2;
    const int i0   = slice*48;
    #pragma unroll 4
    for (int ii = 0; ii < 48; ++ii) {
      const int i = i0 + ii;
      const float4 w = w24[(size_t)i*rowq + jc];
      #pragma unroll
      for (int b = 0; b < 8; ++b) {
        const float hv = hs[b*D_ + i];
        acc[b][0] = fmaf(hv, w.x, acc[b][0]);
        acc[b][1] = fmaf(hv, w.y, acc[b][1]);
        acc[b][2] = fmaf(hv, w.z, acc[b][2]);
        acc[b][3] = fmaf(hv, w.w, acc[b][3]);
      }
    }
  }
  #pragma unroll
  for (int b = 0; b < 8; ++b) {
    #pragma unroll
    for (int q = 0; q < 4; ++q) {
      float v = acc[b][q];
      v += __shfl_xor(v, 16, 64);
      v += __shfl_xor(v, 32, 64);
      acc[b][q] = v;
    }
  }
  const int wv = tid >> 6;
  if ((tid & 63) < 16) {
    #pragma unroll
    for (int b = 0; b < 8; ++b)
      #pragma unroll
      for (int q = 0; q < 4; ++q)
        red[wv][jg][b*4+q] = acc[b][q];
  }
  __syncthreads();
  for (int s = tid; s < 512; s += 256) {
    const int jg2 = s >> 5;
    const int v2  = s & 31;
    const int b   = v2 >> 2, q = v2 & 3;
    const int jo  = j0 + jg2*4 + q;
    if (jo < Jmax) {
      const float sum = red[0][jg2][v2] + red[1][jg2][v2]
                      + red[2][jg2][v2] + red[3][jg2][v2];
      mo[(size_t)b*Jmax + jo] = tanhf(sum + b2[jo]);
    }
  }
}

// ---------------------------------------------------------------- spectral
// One block per COLUMN PAIR (d, d+1): two-for-one packed real FFT.
// XCD swizzle: all 32 dp-blocks of one (b,h) land on the same XCD for L2 reuse.
// xc buffers double as overlap-add accumulators (even phase assigns).
__global__ __launch_bounds__(256) void k_spectral(
    const float* __restrict__ x,
    const float* __restrict__ bfg, const float* __restrict__ bfl,
    const float* __restrict__ mbg, const float* __restrict__ mbl,
    const float* __restrict__ mg,  const float* __restrict__ ml,
    const float* __restrict__ fw,  float* __restrict__ fused) {
  __shared__ float2 cb[N_ + (N_>>4)];       // swizzled complex buffer (17.4 KB)
  __shared__ float2 tw[1024];               // tw[m] = exp(-i*pi*m/1024) (8 KB)
  __shared__ float  xc1[N_ + (N_>>3)], xc2[N_ + (N_>>3)];  // x copy, then overlap-add acc
  __shared__ float  ct16[16], st16[16], hw[16];

  const int tid = threadIdx.x;
  const int id  = blockIdx.x;               // 3072
  const int v_  = (id & 7) * 384 + (id >> 3);   // XCD-resident remap
  const int dp  = v_ & 31;
  const int bh  = v_ >> 5;
  const int h   = bh % H_;
  const int b   = bh / H_;
  const int d   = dp * 2;
  const int c   = h*HD_ + d;
  const int col0 = bh*HD_ + d;              // row in fused (== b*D + c)

  for (int m = tid; m < 1024; m += 256) {
    float s_, c_;
    sincospif(-(float)m * (1.0f/1024.0f), &s_, &c_);
    tw[m] = make_float2(c_, s_);
  }
  if (tid < 16) {
    float s_, c_;
    sincospif((float)tid * 0.125f, &s_, &c_);
    ct16[tid] = c_; st16[tid] = s_;
    hw[tid] = 0.5f*(1.0f - c_);
  }
  for (int n = tid; n < N_; n += 256) {
    const float2 v = *(const float2*)&x[((size_t)(b*N_ + n))*D_ + c];
    xc1[XS(n)] = v.x; xc2[XS(n)] = v.y;
    cb[CBX(n)] = v;                          // z = x_d + i*x_{d+1}
  }
  __syncthreads();

  // ---- forward FFT: radix-2 DIF, stages paired (natural in -> bitrev out) ----
  #pragma unroll
  for (int sh = 10; sh >= 2; sh -= 2) {
    const int hspan = 1 << sh, hh = hspan >> 1;
    for (int t = tid; t < 512; t += 256) {
      const int p  = t & (hh-1);
      const int g  = t >> (sh-1);
      const int i0 = (g << (sh+1)) | p;
      float2 a = cb[CBX(i0)], bb = cb[CBX(i0+hh)], cc = cb[CBX(i0+hspan)], dd = cb[CBX(i0+hspan+hh)];
      const float2 w1  = tw[p << (10-sh)];
      const float2 w1b = tw[(p+hh) << (10-sh)];
      const float2 w2  = tw[p << (11-sh)];
      float2 ap = caddf(a, cc),  cp = cmulf(csubf(a, cc), w1);
      float2 bp = caddf(bb, dd), dp2 = cmulf(csubf(bb, dd), w1b);
      cb[CBX(i0)]          = caddf(ap, bp);
      cb[CBX(i0+hh)]       = cmulf(csubf(ap, bp), w2);
      cb[CBX(i0+hspan)]    = caddf(cp, dp2);
      cb[CBX(i0+hspan+hh)] = cmulf(csubf(cp, dp2), w2);
    }
    __syncthreads();
  }
  for (int t = tid; t < 1024; t += 256) {
    const int i0 = t << 1;
    float2 a = cb[CBX(i0)], bb = cb[CBX(i0+1)];
    cb[CBX(i0)]   = caddf(a, bb);
    cb[CBX(i0+1)] = csubf(a, bb);
  }
  __syncthreads();

  // ---- separate packed spectra, filter+modrelu both, repack (bitrev domain) ----
  const float fsc = 0.022097086912079610f;   // 1/sqrt(2048)
  {
    const float* mgp = mg + (size_t)b*(H_*GB_) + h*GB_;
    const float* bfp = bfg + h*GB_;
    const float* mbp = mbg + h*GB_;
    for (int k = tid; k < 1024; k += 256) {
      if (k == 0) {
        float2 Z0 = cb[CBX(0)], Zn = cb[CBX(1)];
        float g1 = Z0.x * fsc, g2 = Z0.y * fsc;
        {
          const float filt = bfp[0] + mgp[0], bias = mbp[0];
          g1 *= filt; g2 *= filt;
          float a1 = fabsf(g1); g1 *= fmaxf(a1 + bias, 0.0f) / fmaxf(a1, 1e-6f);
          float a2 = fabsf(g2); g2 *= fmaxf(a2 + bias, 0.0f) / fmaxf(a2, 1e-6f);
        }
        cb[CBX(0)] = make_float2(g1, g2);
        float n1 = Zn.x * fsc, n2 = Zn.y * fsc;
        {
          const float filt = bfp[1024] + mgp[1024], bias = mbp[1024];
          n1 *= filt; n2 *= filt;
          float a1 = fabsf(n1); n1 *= fmaxf(a1 + bias, 0.0f) / fmaxf(a1, 1e-6f);
          float a2 = fabsf(n2); n2 *= fmaxf(a2 + bias, 0.0f) / fmaxf(a2, 1e-6f);
        }
        cb[CBX(1)] = make_float2(n1, n2);
      } else {
        const int ik  = (int)(__brev((unsigned)k) >> 21);
        const int imk = (int)(__brev((unsigned)(2048 - k)) >> 21);
        const float2 Za = cb[CBX(ik)], Zb = cb[CBX(imk)];
        const float hs_ = 0.5f * fsc;
        float f1r = (Za.x + Zb.x) * hs_, f1i = (Za.y - Zb.y) * hs_;
        float f2r = (Za.y + Zb.y) * hs_, f2i = (Zb.x - Za.x) * hs_;
        const float filt = bfp[k] + mgp[k], bias = mbp[k];
        f1r *= filt; f1i *= filt; f2r *= filt; f2i *= filt;
        const float a1 = sqrtf(f1r*f1r + f1i*f1i);
        const float s1 = fmaxf(a1 + bias, 0.0f) / fmaxf(a1, 1e-6f);
        f1r *= s1; f1i *= s1;
        const float a2 = sqrtf(f2r*f2r + f2i*f2i);
        const float s2 = fmaxf(a2 + bias, 0.0f) / fmaxf(a2, 1e-6f);
        f2r *= s2; f2i *= s2;
        cb[CBX(ik)]  = make_float2(f1r - f2i, f1i + f2r);
        cb[CBX(imk)] = make_float2(f1r + f2i, f2r - f1i);
      }
    }
  }
  __syncthreads();

  // ---- inverse FFT: radix-2 DIT (bitrev in -> natural out) ----
  for (int t = tid; t < 1024; t += 256) {
    const int i0 = t << 1;
    float2 a = cb[CBX(i0)], bb = cb[CBX(i0+1)];
    cb[CBX(i0)]   = caddf(a, bb);
    cb[CBX(i0+1)] = csubf(a, bb);
  }
  __syncthreads();
  #pragma unroll
  for (int sh = 2; sh <= 10; sh += 2) {
    const int hspan = 1 << sh, hh = hspan >> 1;
    for (int t = tid; t < 512; t += 256) {
      const int p  = t & (hh-1);
      const int g  = t >> (sh-1);
      const int i0 = (g << (sh+1)) | p;
      float2 a = cb[CBX(i0)], bb = cb[CBX(i0+hh)], cc = cb[CBX(i0+hspan)], dd = cb[CBX(i0+hspan+hh)];
      float2 w2  = tw[p << (11-sh)];       w2.y  = -w2.y;
      float2 w1  = tw[p << (10-sh)];       w1.y  = -w1.y;
      float2 w1b = tw[(p+hh) << (10-sh)];  w1b.y = -w1b.y;
      float2 t1 = cmulf(bb, w2);
      float2 ap = caddf(a, t1),  bp = csubf(a, t1);
      float2 t2 = cmulf(dd, w2);
      float2 cp = caddf(cc, t2), dp2 = csubf(cc, t2);
      float2 T = cmulf(cp, w1);
      float2 U = cmulf(dp2, w1b);
      cb[CBX(i0)]          = caddf(ap, T);
      cb[CBX(i0+hspan)]    = csubf(ap, T);
      cb[CBX(i0+hh)]       = caddf(bp, U);
      cb[CBX(i0+hspan+hh)] = csubf(bp, U);
    }
    __syncthreads();
  }

  // ---- local windowed path; xc buffer becomes the overlap-add accumulator ----
  const float* blp = bfl + h*LB_;
  const float* mlp = ml + (size_t)b*(H_*LB_) + h*LB_;
  const float* mbl_p = mbl + h*LB_;
  #pragma unroll
  for (int cc = 0; cc < 2; ++cc) {
    float* xs = cc ? xc2 : xc1;   // read x, then reused as accumulator
    float outw[16];
    const int j = tid;
    if (j < NW_) {
      float y[16];
      #pragma unroll
      for (int t = 0; t < 16; ++t) y[t] = xs[XS(j*8 + t)] * hw[t];
      float cr[9], ci[9];
      #pragma unroll
      for (int l = 0; l <= 8; ++l) {
        float sr = 0.0f, si = 0.0f;
        #pragma unroll
        for (int t = 0; t < 16; ++t) {
          const int m = (l*t) & 15;
          sr = fmaf(y[t],  ct16[m], sr);
          si = fmaf(-y[t], st16[m], si);
        }
        sr *= 0.25f; si *= 0.25f;
        const float filt = blp[l] + mlp[l];
        sr *= filt; si *= filt;
        const float a = sqrtf(sr*sr + si*si);
        const float f = fmaxf(a + mbl_p[l], 0.0f) / fmaxf(a, 1e-6f);
        cr[l] = sr*f; ci[l] = si*f;
      }
      #pragma unroll
      for (int t = 0; t < 16; ++t) {
        float acc = cr[0] + cr[8]*ct16[(8*t) & 15];
        #pragma unroll
        for (int l = 1; l <= 7; ++l) {
          const int m = (l*t) & 15;
          acc += 2.0f*(cr[l]*ct16[m] - ci[l]*st16[m]);
        }
        outw[t] = acc * 0.25f * hw[t];
      }
    }
    __syncthreads();
    if (j < NW_ && !(j & 1)) {   // even windows tile [0,2048) exactly: ASSIGN over stale x
      #pragma unroll
      for (int t = 0; t < 16; ++t) xs[XS(j*8 + t)] = outw[t];
    }
    __syncthreads();
    if (j < NW_ && (j & 1)) {
      #pragma unroll
      for (int t = 0; t < 16; ++t) xs[XS(j*8 + t)] += outw[t];
    }
    __syncthreads();
  }

  const float fw0 = fw[0], fw1 = fw[1];
  float* f0 = fused + (size_t)col0 * N_;
  float* f1 = f0 + N_;
  for (int n = tid; n < N_; n += 256) {
    const float2 v = cb[CBX(n)];
    f0[n] = fw0 * (v.x * fsc) + fw1 * xc1[XS(n)];
    f1[n] = fw0 * (v.y * fsc) + fw1 * xc2[XS(n)];
  }
}

// ---------------------------------------------------------------- residual + LayerNorm
__global__ __launch_bounds__(256) void k_ln(const float* __restrict__ x,
                                            const float* __restrict__ fused,
                                            const float* __restrict__ gamma,
                                            const float* __restrict__ beta,
                                            float* __restrict__ out) {
  __shared__ float yt[16*772];
  __shared__ float mus[16], rsd[16];
  const int bi = blockIdx.x;
  const int b  = bi >> 7;
  const int n0 = (bi & 127) * 16;
  const int tid = threadIdx.x;

  {
    const float4* x4 = (const float4*)(x + ((size_t)(b*N_ + n0))*D_);
    for (int i = tid; i < 16*D_/4; i += 256) {
      const int nn = i / 192, r = i - nn*192;
      const float4 v = x4[i];
      float* yp = &yt[nn*772 + r*4];
      yp[0] = v.x; yp[1] = v.y; yp[2] = v.z; yp[3] = v.w;
    }
  }
  __syncthreads();
  {
    const float4* fu4 = (const float4*)fused;
    for (int i = tid; i < 16*D_/4; i += 256) {
      const int cc = i >> 2, q = (i & 3) * 4;
      const float4 g = fu4[(((size_t)(b*D_ + cc))*N_ + n0)/4 + (i & 3)];
      yt[(q+0)*772 + cc] += g.x;
      yt[(q+1)*772 + cc] += g.y;
      yt[(q+2)*772 + cc] += g.z;
      yt[(q+3)*772 + cc] += g.w;
    }
  }
  __syncthreads();
  const int nn = tid >> 4, cl = tid & 15;
  float s1 = 0.0f, s2 = 0.0f;
  for (int c = cl; c < D_; c += 16) {
    const float v = yt[nn*772 + c];
    s1 += v; s2 += v*v;
  }
  #pragma unroll
  for (int m = 8; m >= 1; m >>= 1) {
    s1 += __shfl_xor(s1, m, 16);
    s2 += __shfl_xor(s2, m, 16);
  }
  if (cl == 0) {
    const float mu  = s1 * (1.0f/(float)D_);
    const float var = s2 * (1.0f/(float)D_) - mu*mu;
    mus[nn] = mu;
    rsd[nn] = rsqrtf(var + 1e-5f);
  }
  __syncthreads();
  {
    float4* o4 = (float4*)(out + ((size_t)(b*N_ + n0))*D_);
    const float4* g4 = (const float4*)gamma;
    const float4* be4 = (const float4*)beta;
    for (int i = tid; i < 16*D_/4; i += 256) {
      const int nn2 = i / 192, r = i - nn2*192;
      const float mu = mus[nn2], rs = rsd[nn2];
      const float4 gm = g4[r], bt = be4[r];
      const float* yp = &yt[nn2*772 + r*4];
      float4 o;
      o.x = (yp[0] - mu) * rs * gm.x + bt.x;
      o.y = (yp[1] - mu) * rs * gm.y + bt.y;
      o.z = (yp[2] - mu) * rs * gm.z + bt.z;
      o.w = (yp[3] - mu) * rs * gm.w + bt.w;
      o4[i] = o;
    }
  }
}

// ---------------------------------------------------------------- launch
extern "C" void kernel_launch(void* const* d_in, const int* in_sizes, int n_in,
                              void* d_out, int out_size, void* d_ws, size_t ws_size,
                              hipStream_t stream) {
  const float* x   = (const float*)d_in[0];
  const float* bfg = (const float*)d_in[1];
  const float* bfl = (const float*)d_in[2];
  const float* mbg = (const float*)d_in[3];
  const float* mbl = (const float*)d_in[4];
  const float* w1g = (const float*)d_in[5];
  const float* b1g = (const float*)d_in[6];
  const float* w2g = (const float*)d_in[7];
  const float* b2g = (const float*)d_in[8];
  const float* w1l = (const float*)d_in[9];
  const float* b1l = (const float*)d_in[10];
  const float* w2l = (const float*)d_in[11];
  const float* b2l = (const float*)d_in[12];
  const float* fw  = (const float*)d_in[13];
  const float* gam = (const float*)d_in[14];
  const float* bet = (const float*)d_in[15];
  float* out = (float*)d_out;

  float* ws    = (float*)d_ws;
  float* ctx   = ws;                 // 6144
  float* h1g   = ws + 6144;
  float* h1l   = ws + 12288;
  float* mg    = ws + 18432;         // 98400
  float* ml    = ws + 116832;        // 864
  float* fused = ws + 117696;        // 8*768*2048

  hipMemsetAsync(ctx, 0, (size_t)B_*D_*sizeof(float), stream);
  k_ctx<<<dim3(B_, 32), 256, 0, stream>>>(x, ctx);
  k_mlp1<<<dim3(12, 2), 256, 0, stream>>>(ctx, w1g, b1g, w1l, b1l, h1g, h1l);
  k_mlp2<<<195, 256, 0, stream>>>(h1g, h1l, w2g, b2g, w2l, b2l, mg, ml);
  k_spectral<<<B_*H_*32, 256, 0, stream>>>(x, bfg, bfl, mbg, mbl, mg, ml, fw, fused);
  k_ln<<<B_*N_/16, 256, 0, stream>>>(x, fused, gam, bet, out);
}

// Round 5
// 332.887 us; speedup vs baseline: 2.3831x; 1.1285x over previous
//
#include <hip/hip_runtime.h>
#include <math.h>

#define B_  8
#define N_  2048
#define D_  768
#define H_  12
#define HD_ 64
#define GB_ 1025
#define LB_ 9
#define NW_ 255

// LDS swizzles (bank-conflict breakers)
#define CBX(i) ((i) + ((i) >> 4))      // float2 array, pad every 16
#define XS(i)  ((i) + ((i) >> 3))      // float array, pad every 8

// FFT16 constants
#define C1_ 0.92387953251128674f
#define S1_ 0.38268343236508978f
#define R2_ 0.70710678118654752f

// forward DIF butterflies (twiddle e^{-i*theta}) on yr/yi register arrays
#define FBF(i,k,wr,wi) { const float ar=yr[i],ai=yi[i],br=yr[k],bi=yi[k]; \
  yr[i]=ar+br; yi[i]=ai+bi; const float dr=ar-br, di=ai-bi; \
  yr[k]=fmaf(dr,wr,-(di*(wi))); yi[k]=fmaf(dr,wi,di*(wr)); }
#define FBF1(i,k) { const float ar=yr[i],ai=yi[i],br=yr[k],bi=yi[k]; \
  yr[i]=ar+br; yi[i]=ai+bi; yr[k]=ar-br; yi[k]=ai-bi; }
#define FBFmi(i,k) { const float ar=yr[i],ai=yi[i],br=yr[k],bi=yi[k]; \
  yr[i]=ar+br; yi[i]=ai+bi; yr[k]=ai-bi; yi[k]=br-ar; }

// inverse DIT butterflies (twiddle e^{+i*theta})
#define IBF(i,k,wr,wi) { const float br=yr[k],bi=yi[k]; \
  const float tr=fmaf(br,wr,-(bi*(wi))), ti=fmaf(br,wi,bi*(wr)); \
  yr[k]=yr[i]-tr; yi[k]=yi[i]-ti; yr[i]+=tr; yi[i]+=ti; }
#define IBF1(i,k) { const float tr=yr[k], ti=yi[k]; \
  yr[k]=yr[i]-tr; yi[k]=yi[i]-ti; yr[i]+=tr; yi[i]+=ti; }
#define IBFpi(i,k) { const float tr=-yi[k], ti=yr[k]; \
  yr[k]=yr[i]-tr; yi[k]=yi[i]-ti; yr[i]+=tr; yi[i]+=ti; }

__device__ __forceinline__ float2 cmulf(float2 a, float2 b) {
  return make_float2(fmaf(a.x, b.x, -(a.y*b.y)), fmaf(a.x, b.y, a.y*b.x));
}
__device__ __forceinline__ float2 caddf(float2 a, float2 b){ return make_float2(a.x+b.x, a.y+b.y); }
__device__ __forceinline__ float2 csubf(float2 a, float2 b){ return make_float2(a.x-b.x, a.y-b.y); }

// ---------------------------------------------------------------- ctx mean
__global__ __launch_bounds__(256) void k_ctx(const float* __restrict__ x,
                                             float* __restrict__ ctx) {
  const int b = blockIdx.x;
  const int nc = blockIdx.y;
  const int tid = threadIdx.x;
  const int n0 = nc * 64;
  for (int c = tid; c < D_; c += 256) {
    float s = 0.0f;
    #pragma unroll 4
    for (int n = 0; n < 64; ++n)
      s += x[((size_t)(b*N_ + n0 + n))*D_ + c];
    atomicAdd(&ctx[b*D_ + c], s);
  }
}

// ---------------------------------------------------------------- mlp layer 1 (gelu)
__global__ __launch_bounds__(256) void k_mlp1(
    const float* __restrict__ ctx,
    const float* __restrict__ w1g, const float* __restrict__ b1g,
    const float* __restrict__ w1l, const float* __restrict__ b1l,
    float* __restrict__ h1g, float* __restrict__ h1l) {
  __shared__ float hs[B_*D_];
  __shared__ float red[4][16][33];
  const int tid = threadIdx.x;
  const bool isl = (blockIdx.y != 0);
  const float* w1 = isl ? w1l : w1g;
  const float* b1 = isl ? b1l : b1g;
  float*       h1 = isl ? h1l : h1g;
  const int j0 = (int)blockIdx.x * 64;

  for (int i = tid; i < B_*D_; i += 256) hs[i] = ctx[i] * (1.0f/(float)N_);
  __syncthreads();

  const int jg    = tid & 15;
  const int slice = tid >> 4;
  const int j     = j0 + jg*4;
  float acc[8][4] = {};
  {
    const float4* w14 = (const float4*)w1;
    const int jc = j >> 2;
    const int i0 = slice*48;
    #pragma unroll 4
    for (int ii = 0; ii < 48; ++ii) {
      const int i = i0 + ii;
      const float4 w = w14[(size_t)i*192 + jc];
      #pragma unroll
      for (int b = 0; b < 8; ++b) {
        const float hv = hs[b*D_ + i];
        acc[b][0] = fmaf(hv, w.x, acc[b][0]);
        acc[b][1] = fmaf(hv, w.y, acc[b][1]);
        acc[b][2] = fmaf(hv, w.z, acc[b][2]);
        acc[b][3] = fmaf(hv, w.w, acc[b][3]);
      }
    }
  }
  #pragma unroll
  for (int b = 0; b < 8; ++b) {
    #pragma unroll
    for (int q = 0; q < 4; ++q) {
      float v = acc[b][q];
      v += __shfl_xor(v, 16, 64);
      v += __shfl_xor(v, 32, 64);
      acc[b][q] = v;
    }
  }
  const int wv = tid >> 6;
  if ((tid & 63) < 16) {
    #pragma unroll
    for (int b = 0; b < 8; ++b)
      #pragma unroll
      for (int q = 0; q < 4; ++q)
        red[wv][jg][b*4+q] = acc[b][q];
  }
  __syncthreads();
  for (int s = tid; s < 512; s += 256) {
    const int jg2 = s >> 5;
    const int v2  = s & 31;
    const int b   = v2 >> 2, q = v2 & 3;
    const int jo  = j0 + jg2*4 + q;
    const float sum = red[0][jg2][v2] + red[1][jg2][v2]
                    + red[2][jg2][v2] + red[3][jg2][v2];
    const float v = sum + b1[jo];
    h1[(size_t)b*D_ + jo] = 0.5f * v * (1.0f + erff(v * 0.70710678118654752f));
  }
}

// ---------------------------------------------------------------- mlp layer 2 (tanh)
__global__ __launch_bounds__(256) void k_mlp2(
    const float* __restrict__ h1g, const float* __restrict__ h1l,
    const float* __restrict__ w2g, const float* __restrict__ b2g,
    const float* __restrict__ w2l, const float* __restrict__ b2l,
    float* __restrict__ mg, float* __restrict__ ml) {
  __shared__ float hs[B_*D_];
  __shared__ float red[4][16][33];
  const int tid = threadIdx.x;
  const bool isg = (blockIdx.x < 193);
  const float* h1 = isg ? h1g : h1l;
  const float* w2 = isg ? w2g : w2l;
  const float* b2 = isg ? b2g : b2l;
  float*       mo = isg ? mg  : ml;
  const int Jmax = isg ? (H_*GB_) : (H_*LB_);
  const int j0   = isg ? (int)blockIdx.x*64 : ((int)blockIdx.x-193)*64;

  for (int i = tid; i < B_*D_; i += 256) hs[i] = h1[i];
  __syncthreads();

  const int jg    = tid & 15;
  const int slice = tid >> 4;
  const int j     = j0 + jg*4;
  float acc[8][4] = {};
  if (j < Jmax) {
    const float4* w24 = (const float4*)w2;
    const int jc   = j >> 2;
    const int rowq = Jmax >> 2;
    const int i0   = slice*48;
    #pragma unroll 4
    for (int ii = 0; ii < 48; ++ii) {
      const int i = i0 + ii;
      const float4 w = w24[(size_t)i*rowq + jc];
      #pragma unroll
      for (int b = 0; b < 8; ++b) {
        const float hv = hs[b*D_ + i];
        acc[b][0] = fmaf(hv, w.x, acc[b][0]);
        acc[b][1] = fmaf(hv, w.y, acc[b][1]);
        acc[b][2] = fmaf(hv, w.z, acc[b][2]);
        acc[b][3] = fmaf(hv, w.w, acc[b][3]);
      }
    }
  }
  #pragma unroll
  for (int b = 0; b < 8; ++b) {
    #pragma unroll
    for (int q = 0; q < 4; ++q) {
      float v = acc[b][q];
      v += __shfl_xor(v, 16, 64);
      v += __shfl_xor(v, 32, 64);
      acc[b][q] = v;
    }
  }
  const int wv = tid >> 6;
  if ((tid & 63) < 16) {
    #pragma unroll
    for (int b = 0; b < 8; ++b)
      #pragma unroll
      for (int q = 0; q < 4; ++q)
        red[wv][jg][b*4+q] = acc[b][q];
  }
  __syncthreads();
  for (int s = tid; s < 512; s += 256) {
    const int jg2 = s >> 5;
    const int v2  = s & 31;
    const int b   = v2 >> 2, q = v2 & 3;
    const int jo  = j0 + jg2*4 + q;
    if (jo < Jmax) {
      const float sum = red[0][jg2][v2] + red[1][jg2][v2]
                      + red[2][jg2][v2] + red[3][jg2][v2];
      mo[(size_t)b*Jmax + jo] = tanhf(sum + b2[jo]);
    }
  }
}

// ---------------------------------------------------------------- spectral
// One block per COLUMN PAIR (d, d+1): two-for-one packed real FFT (global) and
// two-for-one packed register FFT16 (local windows, literal twiddles).
__global__ __launch_bounds__(256) void k_spectral(
    const float* __restrict__ x,
    const float* __restrict__ bfg, const float* __restrict__ bfl,
    const float* __restrict__ mbg, const float* __restrict__ mbl,
    const float* __restrict__ mg,  const float* __restrict__ ml,
    const float* __restrict__ fw,  float* __restrict__ fused) {
  __shared__ float2 cb[N_ + (N_>>4)];       // swizzled complex buffer
  __shared__ float2 tw[1024];               // tw[m] = exp(-i*pi*m/1024)
  __shared__ float  xc1[N_ + (N_>>3)], xc2[N_ + (N_>>3)];  // x copy -> overlap-add acc
  __shared__ float  lf[LB_], lb[LB_];       // local filter / bias (per (b,h))

  const int tid = threadIdx.x;
  const int id  = blockIdx.x;               // 3072
  const int v_  = (id & 7) * 384 + (id >> 3);   // XCD-resident remap
  const int dp  = v_ & 31;
  const int bh  = v_ >> 5;
  const int h   = bh % H_;
  const int b   = bh / H_;
  const int d   = dp * 2;
  const int c   = h*HD_ + d;
  const int col0 = bh*HD_ + d;

  for (int m = tid; m < 1024; m += 256) {
    float s_, c_;
    sincospif(-(float)m * (1.0f/1024.0f), &s_, &c_);
    tw[m] = make_float2(c_, s_);
  }
  if (tid < LB_) {
    lf[tid] = bfl[h*LB_ + tid] + ml[(size_t)b*(H_*LB_) + h*LB_ + tid];
    lb[tid] = mbl[h*LB_ + tid];
  }
  for (int n = tid; n < N_; n += 256) {
    const float2 v = *(const float2*)&x[((size_t)(b*N_ + n))*D_ + c];
    xc1[XS(n)] = v.x; xc2[XS(n)] = v.y;
    cb[CBX(n)] = v;                          // z = x_d + i*x_{d+1}
  }
  __syncthreads();

  // ---- forward FFT: radix-2 DIF, stages paired (natural in -> bitrev out) ----
  #pragma unroll
  for (int sh = 10; sh >= 2; sh -= 2) {
    const int hspan = 1 << sh, hh = hspan >> 1;
    for (int t = tid; t < 512; t += 256) {
      const int p  = t & (hh-1);
      const int g  = t >> (sh-1);
      const int i0 = (g << (sh+1)) | p;
      float2 a = cb[CBX(i0)], bb = cb[CBX(i0+hh)], cc = cb[CBX(i0+hspan)], dd = cb[CBX(i0+hspan+hh)];
      const float2 w1  = tw[p << (10-sh)];
      const float2 w1b = tw[(p+hh) << (10-sh)];
      const float2 w2  = tw[p << (11-sh)];
      float2 ap = caddf(a, cc),  cp = cmulf(csubf(a, cc), w1);
      float2 bp = caddf(bb, dd), dp2 = cmulf(csubf(bb, dd), w1b);
      cb[CBX(i0)]          = caddf(ap, bp);
      cb[CBX(i0+hh)]       = cmulf(csubf(ap, bp), w2);
      cb[CBX(i0+hspan)]    = caddf(cp, dp2);
      cb[CBX(i0+hspan+hh)] = cmulf(csubf(cp, dp2), w2);
    }
    __syncthreads();
  }
  for (int t = tid; t < 1024; t += 256) {
    const int i0 = t << 1;
    float2 a = cb[CBX(i0)], bb = cb[CBX(i0+1)];
    cb[CBX(i0)]   = caddf(a, bb);
    cb[CBX(i0+1)] = csubf(a, bb);
  }
  __syncthreads();

  // ---- separate packed spectra, filter+modrelu both, repack (bitrev domain) ----
  const float fsc = 0.022097086912079610f;   // 1/sqrt(2048)
  {
    const float* mgp = mg + (size_t)b*(H_*GB_) + h*GB_;
    const float* bfp = bfg + h*GB_;
    const float* mbp = mbg + h*GB_;
    for (int k = tid; k < 1024; k += 256) {
      if (k == 0) {
        float2 Z0 = cb[CBX(0)], Zn = cb[CBX(1)];
        float g1 = Z0.x * fsc, g2 = Z0.y * fsc;
        {
          const float filt = bfp[0] + mgp[0], bias = mbp[0];
          g1 *= filt; g2 *= filt;
          float a1 = fabsf(g1); g1 *= fmaxf(a1 + bias, 0.0f) / fmaxf(a1, 1e-6f);
          float a2 = fabsf(g2); g2 *= fmaxf(a2 + bias, 0.0f) / fmaxf(a2, 1e-6f);
        }
        cb[CBX(0)] = make_float2(g1, g2);
        float n1 = Zn.x * fsc, n2 = Zn.y * fsc;
        {
          const float filt = bfp[1024] + mgp[1024], bias = mbp[1024];
          n1 *= filt; n2 *= filt;
          float a1 = fabsf(n1); n1 *= fmaxf(a1 + bias, 0.0f) / fmaxf(a1, 1e-6f);
          float a2 = fabsf(n2); n2 *= fmaxf(a2 + bias, 0.0f) / fmaxf(a2, 1e-6f);
        }
        cb[CBX(1)] = make_float2(n1, n2);
      } else {
        const int ik  = (int)(__brev((unsigned)k) >> 21);
        const int imk = (int)(__brev((unsigned)(2048 - k)) >> 21);
        const float2 Za = cb[CBX(ik)], Zb = cb[CBX(imk)];
        const float hs_ = 0.5f * fsc;
        float f1r = (Za.x + Zb.x) * hs_, f1i = (Za.y - Zb.y) * hs_;
        float f2r = (Za.y + Zb.y) * hs_, f2i = (Zb.x - Za.x) * hs_;
        const float filt = bfp[k] + mgp[k], bias = mbp[k];
        f1r *= filt; f1i *= filt; f2r *= filt; f2i *= filt;
        const float a1 = sqrtf(f1r*f1r + f1i*f1i);
        const float s1 = fmaxf(a1 + bias, 0.0f) / fmaxf(a1, 1e-6f);
        f1r *= s1; f1i *= s1;
        const float a2 = sqrtf(f2r*f2r + f2i*f2i);
        const float s2 = fmaxf(a2 + bias, 0.0f) / fmaxf(a2, 1e-6f);
        f2r *= s2; f2i *= s2;
        cb[CBX(ik)]  = make_float2(f1r - f2i, f1i + f2r);
        cb[CBX(imk)] = make_float2(f1r + f2i, f2r - f1i);
      }
    }
  }
  __syncthreads();

  // ---- inverse FFT: radix-2 DIT (bitrev in -> natural out) ----
  for (int t = tid; t < 1024; t += 256) {
    const int i0 = t << 1;
    float2 a = cb[CBX(i0)], bb = cb[CBX(i0+1)];
    cb[CBX(i0)]   = caddf(a, bb);
    cb[CBX(i0+1)] = csubf(a, bb);
  }
  __syncthreads();
  #pragma unroll
  for (int sh = 2; sh <= 10; sh += 2) {
    const int hspan = 1 << sh, hh = hspan >> 1;
    for (int t = tid; t < 512; t += 256) {
      const int p  = t & (hh-1);
      const int g  = t >> (sh-1);
      const int i0 = (g << (sh+1)) | p;
      float2 a = cb[CBX(i0)], bb = cb[CBX(i0+hh)], cc = cb[CBX(i0+hspan)], dd = cb[CBX(i0+hspan+hh)];
      float2 w2  = tw[p << (11-sh)];       w2.y  = -w2.y;
      float2 w1  = tw[p << (10-sh)];       w1.y  = -w1.y;
      float2 w1b = tw[(p+hh) << (10-sh)];  w1b.y = -w1b.y;
      float2 t1 = cmulf(bb, w2);
      float2 ap = caddf(a, t1),  bp = csubf(a, t1);
      float2 t2 = cmulf(dd, w2);
      float2 cp = caddf(cc, t2), dp2 = csubf(cc, t2);
      float2 T = cmulf(cp, w1);
      float2 U = cmulf(dp2, w1b);
      cb[CBX(i0)]          = caddf(ap, T);
      cb[CBX(i0+hspan)]    = csubf(ap, T);
      cb[CBX(i0+hh)]       = caddf(bp, U);
      cb[CBX(i0+hspan+hh)] = csubf(bp, U);
    }
    __syncthreads();
  }

  // ---- local windowed path: packed complex FFT16 in registers, both columns at once ----
  const float HWIN[16] = {0.0f, 0.038060233744356624f, 0.14644660940672624f, 0.30865828381745508f,
                          0.5f, 0.69134171618254492f, 0.85355339059327376f, 0.96193976625564337f,
                          1.0f, 0.96193976625564337f, 0.85355339059327376f, 0.69134171618254492f,
                          0.5f, 0.30865828381745508f, 0.14644660940672624f, 0.038060233744356624f};
  float yr[16], yi[16];
  const int j = tid;
  if (j < NW_) {
    #pragma unroll
    for (int t = 0; t < 16; ++t) {
      yr[t] = xc1[XS(j*8 + t)] * HWIN[t];
      yi[t] = xc2[XS(j*8 + t)] * HWIN[t];
    }
    // forward FFT16 (DIF, natural -> bitrev)
    FBF1(0,8); FBF(1,9,C1_,-S1_); FBF(2,10,R2_,-R2_); FBF(3,11,S1_,-C1_);
    FBFmi(4,12); FBF(5,13,-S1_,-C1_); FBF(6,14,-R2_,-R2_); FBF(7,15,-C1_,-S1_);
    FBF1(0,4); FBF(1,5,R2_,-R2_); FBFmi(2,6); FBF(3,7,-R2_,-R2_);
    FBF1(8,12); FBF(9,13,R2_,-R2_); FBFmi(10,14); FBF(11,15,-R2_,-R2_);
    FBF1(0,2); FBFmi(1,3); FBF1(4,6); FBFmi(5,7);
    FBF1(8,10); FBFmi(9,11); FBF1(12,14); FBFmi(13,15);
    FBF1(0,1); FBF1(2,3); FBF1(4,5); FBF1(6,7);
    FBF1(8,9); FBF1(10,11); FBF1(12,13); FBF1(14,15);
    // separate F1/F2 (bitrev positions), filter+modrelu, repack W (bitrev positions)
    {
      const int IA[9] = {0,8,4,12,2,10,6,14,1};
      const int IB[9] = {0,15,7,11,3,13,5,9,1};
      #pragma unroll
      for (int l = 0; l <= 8; ++l) {
        const int ia = IA[l], ib = IB[l];
        const float Zar=yr[ia], Zai=yi[ia], Zbr=yr[ib], Zbi=yi[ib];
        float f1r = 0.125f*(Zar+Zbr), f1i = 0.125f*(Zai-Zbi);
        float f2r = 0.125f*(Zai+Zbi), f2i = 0.125f*(Zbr-Zar);
        const float ft = lf[l], bs = lb[l];
        f1r *= ft; f1i *= ft; f2r *= ft; f2i *= ft;
        const float a1 = sqrtf(f1r*f1r + f1i*f1i);
        const float m1 = fmaxf(a1 + bs, 0.0f) / fmaxf(a1, 1e-6f);
        f1r *= m1; f1i *= m1;
        const float a2 = sqrtf(f2r*f2r + f2i*f2i);
        const float m2 = fmaxf(a2 + bs, 0.0f) / fmaxf(a2, 1e-6f);
        f2r *= m2; f2i *= m2;
        yr[ia] = f1r - f2i; yi[ia] = f1i + f2r;
        if (l >= 1 && l <= 7) { yr[ib] = f1r + f2i; yi[ib] = f2r - f1i; }
      }
    }
    // inverse FFT16 (DIT, bitrev -> natural)
    IBF1(0,1); IBF1(2,3); IBF1(4,5); IBF1(6,7);
    IBF1(8,9); IBF1(10,11); IBF1(12,13); IBF1(14,15);
    IBF1(0,2); IBFpi(1,3); IBF1(4,6); IBFpi(5,7);
    IBF1(8,10); IBFpi(9,11); IBF1(12,14); IBFpi(13,15);
    IBF1(0,4); IBF(1,5,R2_,R2_); IBFpi(2,6); IBF(3,7,-R2_,R2_);
    IBF1(8,12); IBF(9,13,R2_,R2_); IBFpi(10,14); IBF(11,15,-R2_,R2_);
    IBF1(0,8); IBF(1,9,C1_,S1_); IBF(2,10,R2_,R2_); IBF(3,11,S1_,C1_);
    IBFpi(4,12); IBF(5,13,-S1_,C1_); IBF(6,14,-R2_,R2_); IBF(7,15,-C1_,S1_);
  }
  __syncthreads();
  if (j < NW_ && !(j & 1)) {   // even windows tile [0,2048): ASSIGN over stale x
    #pragma unroll
    for (int t = 0; t < 16; ++t) {
      const float q = 0.25f * HWIN[t];
      xc1[XS(j*8 + t)] = yr[t] * q;
      xc2[XS(j*8 + t)] = yi[t] * q;
    }
  }
  __syncthreads();
  if (j < NW_ && (j & 1)) {
    #pragma unroll
    for (int t = 0; t < 16; ++t) {
      const float q = 0.25f * HWIN[t];
      xc1[XS(j*8 + t)] += yr[t] * q;
      xc2[XS(j*8 + t)] += yi[t] * q;
    }
  }
  __syncthreads();

  const float fw1 = fw[1];
  const float fwg = fw[0] * fsc;
  float* f0 = fused + (size_t)col0 * N_;
  float* f1 = f0 + N_;
  for (int n = tid; n < N_; n += 256) {
    const float2 v = cb[CBX(n)];
    f0[n] = fwg * v.x + fw1 * xc1[XS(n)];
    f1[n] = fwg * v.y + fw1 * xc2[XS(n)];
  }
}

// ---------------------------------------------------------------- residual + LayerNorm
__global__ __launch_bounds__(256) void k_ln(const float* __restrict__ x,
                                            const float* __restrict__ fused,
                                            const float* __restrict__ gamma,
                                            const float* __restrict__ beta,
                                            float* __restrict__ out) {
  __shared__ float yt[16*776];     // stride 776: 776%32==8 -> 2-way max in reduce
  __shared__ float mus[16], rsd[16];
  const int bi = blockIdx.x;
  const int b  = bi >> 7;
  const int n0 = (bi & 127) * 16;
  const int tid = threadIdx.x;

  {
    const float4* x4 = (const float4*)(x + ((size_t)(b*N_ + n0))*D_);
    for (int i = tid; i < 16*D_/4; i += 256) {
      const int nn = i / 192, r = i - nn*192;
      const float4 v = x4[i];
      float* yp = &yt[nn*776 + r*4];
      yp[0] = v.x; yp[1] = v.y; yp[2] = v.z; yp[3] = v.w;
    }
  }
  __syncthreads();
  {
    const float4* fu4 = (const float4*)fused;
    for (int i = tid; i < 16*D_/4; i += 256) {
      const int cc = i >> 2, q = (i & 3) * 4;
      const float4 g = fu4[(((size_t)(b*D_ + cc))*N_ + n0)/4 + (i & 3)];
      yt[(q+0)*776 + cc] += g.x;
      yt[(q+1)*776 + cc] += g.y;
      yt[(q+2)*776 + cc] += g.z;
      yt[(q+3)*776 + cc] += g.w;
    }
  }
  __syncthreads();
  const int nn = tid >> 4, cl = tid & 15;
  float s1 = 0.0f, s2 = 0.0f;
  for (int c = cl; c < D_; c += 16) {
    const float v = yt[nn*776 + c];
    s1 += v; s2 += v*v;
  }
  #pragma unroll
  for (int m = 8; m >= 1; m >>= 1) {
    s1 += __shfl_xor(s1, m, 16);
    s2 += __shfl_xor(s2, m, 16);
  }
  if (cl == 0) {
    const float mu  = s1 * (1.0f/(float)D_);
    const float var = s2 * (1.0f/(float)D_) - mu*mu;
    mus[nn] = mu;
    rsd[nn] = rsqrtf(var + 1e-5f);
  }
  __syncthreads();
  {
    float4* o4 = (float4*)(out + ((size_t)(b*N_ + n0))*D_);
    const float4* g4 = (const float4*)gamma;
    const float4* be4 = (const float4*)beta;
    for (int i = tid; i < 16*D_/4; i += 256) {
      const int nn2 = i / 192, r = i - nn2*192;
      const float mu = mus[nn2], rs = rsd[nn2];
      const float4 gm = g4[r], bt = be4[r];
      const float* yp = &yt[nn2*776 + r*4];
      float4 o;
      o.x = (yp[0] - mu) * rs * gm.x + bt.x;
      o.y = (yp[1] - mu) * rs * gm.y + bt.y;
      o.z = (yp[2] - mu) * rs * gm.z + bt.z;
      o.w = (yp[3] - mu) * rs * gm.w + bt.w;
      o4[i] = o;
    }
  }
}

// ---------------------------------------------------------------- launch
extern "C" void kernel_launch(void* const* d_in, const int* in_sizes, int n_in,
                              void* d_out, int out_size, void* d_ws, size_t ws_size,
                              hipStream_t stream) {
  const float* x   = (const float*)d_in[0];
  const float* bfg = (const float*)d_in[1];
  const float* bfl = (const float*)d_in[2];
  const float* mbg = (const float*)d_in[3];
  const float* mbl = (const float*)d_in[4];
  const float* w1g = (const float*)d_in[5];
  const float* b1g = (const float*)d_in[6];
  const float* w2g = (const float*)d_in[7];
  const float* b2g = (const float*)d_in[8];
  const float* w1l = (const float*)d_in[9];
  const float* b1l = (const float*)d_in[10];
  const float* w2l = (const float*)d_in[11];
  const float* b2l = (const float*)d_in[12];
  const float* fw  = (const float*)d_in[13];
  const float* gam = (const float*)d_in[14];
  const float* bet = (const float*)d_in[15];
  float* out = (float*)d_out;

  float* ws    = (float*)d_ws;
  float* ctx   = ws;                 // 6144
  float* h1g   = ws + 6144;
  float* h1l   = ws + 12288;
  float* mg    = ws + 18432;         // 98400
  float* ml    = ws + 116832;        // 864
  float* fused = ws + 117696;        // 8*768*2048

  hipMemsetAsync(ctx, 0, (size_t)B_*D_*sizeof(float), stream);
  k_ctx<<<dim3(B_, 32), 256, 0, stream>>>(x, ctx);
  k_mlp1<<<dim3(12, 2), 256, 0, stream>>>(ctx, w1g, b1g, w1l, b1l, h1g, h1l);
  k_mlp2<<<195, 256, 0, stream>>>(h1g, h1l, w2g, b2g, w2l, b2l, mg, ml);
  k_spectral<<<B_*H_*32, 256, 0, stream>>>(x, bfg, bfl, mbg, mbl, mg, ml, fw, fused);
  k_ln<<<B_*N_/16, 256, 0, stream>>>(x, fused, gam, bet, out);
}

// Round 6
// 312.479 us; speedup vs baseline: 2.5387x; 1.0653x over previous
//
#include <hip/hip_runtime.h>
#include <math.h>

#define B_  8
#define N_  2048
#define D_  768
#define H_  12
#define HD_ 64
#define GB_ 1025
#define LB_ 9
#define NW_ 255

// LDS swizzles (bank-conflict breakers)
#define CBX(i) ((i) + ((i) >> 4))      // float2 array, pad every 16

// FFT16 constants
#define C1_ 0.92387953251128674f
#define S1_ 0.38268343236508978f
#define R2_ 0.70710678118654752f

// forward DIF butterflies (twiddle e^{-i*theta}) on yr/yi register arrays
#define FBF(i,k,wr,wi) { const float ar=yr[i],ai=yi[i],br=yr[k],bi=yi[k]; \
  yr[i]=ar+br; yi[i]=ai+bi; const float dr=ar-br, di=ai-bi; \
  yr[k]=fmaf(dr,wr,-(di*(wi))); yi[k]=fmaf(dr,wi,di*(wr)); }
#define FBF1(i,k) { const float ar=yr[i],ai=yi[i],br=yr[k],bi=yi[k]; \
  yr[i]=ar+br; yi[i]=ai+bi; yr[k]=ar-br; yi[k]=ai-bi; }
#define FBFmi(i,k) { const float ar=yr[i],ai=yi[i],br=yr[k],bi=yi[k]; \
  yr[i]=ar+br; yi[i]=ai+bi; yr[k]=ai-bi; yi[k]=br-ar; }

// inverse DIT butterflies (twiddle e^{+i*theta})
#define IBF(i,k,wr,wi) { const float br=yr[k],bi=yi[k]; \
  const float tr=fmaf(br,wr,-(bi*(wi))), ti=fmaf(br,wi,bi*(wr)); \
  yr[k]=yr[i]-tr; yi[k]=yi[i]-ti; yr[i]+=tr; yi[i]+=ti; }
#define IBF1(i,k) { const float tr=yr[k], ti=yi[k]; \
  yr[k]=yr[i]-tr; yi[k]=yi[i]-ti; yr[i]+=tr; yi[i]+=ti; }
#define IBFpi(i,k) { const float tr=-yi[k], ti=yr[k]; \
  yr[k]=yr[i]-tr; yi[k]=yi[i]-ti; yr[i]+=tr; yi[i]+=ti; }

__device__ __forceinline__ float2 cmulf(float2 a, float2 b) {
  return make_float2(fmaf(a.x, b.x, -(a.y*b.y)), fmaf(a.x, b.y, a.y*b.x));
}
__device__ __forceinline__ float2 caddf(float2 a, float2 b){ return make_float2(a.x+b.x, a.y+b.y); }
__device__ __forceinline__ float2 csubf(float2 a, float2 b){ return make_float2(a.x-b.x, a.y-b.y); }

// ---------------------------------------------------------------- ctx mean
__global__ __launch_bounds__(256) void k_ctx(const float* __restrict__ x,
                                             float* __restrict__ ctx) {
  const int b = blockIdx.x;
  const int nc = blockIdx.y;
  const int tid = threadIdx.x;
  const int n0 = nc * 64;
  for (int c = tid; c < D_; c += 256) {
    float s = 0.0f;
    #pragma unroll 4
    for (int n = 0; n < 64; ++n)
      s += x[((size_t)(b*N_ + n0 + n))*D_ + c];
    atomicAdd(&ctx[b*D_ + c], s);
  }
}

// ---------------------------------------------------------------- mlp layer 1 (gelu)
__global__ __launch_bounds__(256) void k_mlp1(
    const float* __restrict__ ctx,
    const float* __restrict__ w1g, const float* __restrict__ b1g,
    const float* __restrict__ w1l, const float* __restrict__ b1l,
    float* __restrict__ h1g, float* __restrict__ h1l) {
  __shared__ float hs[B_*D_];
  __shared__ float red[4][16][33];
  const int tid = threadIdx.x;
  const bool isl = (blockIdx.y != 0);
  const float* w1 = isl ? w1l : w1g;
  const float* b1 = isl ? b1l : b1g;
  float*       h1 = isl ? h1l : h1g;
  const int j0 = (int)blockIdx.x * 64;

  for (int i = tid; i < B_*D_; i += 256) hs[i] = ctx[i] * (1.0f/(float)N_);
  __syncthreads();

  const int jg    = tid & 15;
  const int slice = tid >> 4;
  const int j     = j0 + jg*4;
  float acc[8][4] = {};
  {
    const float4* w14 = (const float4*)w1;
    const int jc = j >> 2;
    const int i0 = slice*48;
    #pragma unroll 4
    for (int ii = 0; ii < 48; ++ii) {
      const int i = i0 + ii;
      const float4 w = w14[(size_t)i*192 + jc];
      #pragma unroll
      for (int b = 0; b < 8; ++b) {
        const float hv = hs[b*D_ + i];
        acc[b][0] = fmaf(hv, w.x, acc[b][0]);
        acc[b][1] = fmaf(hv, w.y, acc[b][1]);
        acc[b][2] = fmaf(hv, w.z, acc[b][2]);
        acc[b][3] = fmaf(hv, w.w, acc[b][3]);
      }
    }
  }
  #pragma unroll
  for (int b = 0; b < 8; ++b) {
    #pragma unroll
    for (int q = 0; q < 4; ++q) {
      float v = acc[b][q];
      v += __shfl_xor(v, 16, 64);
      v += __shfl_xor(v, 32, 64);
      acc[b][q] = v;
    }
  }
  const int wv = tid >> 6;
  if ((tid & 63) < 16) {
    #pragma unroll
    for (int b = 0; b < 8; ++b)
      #pragma unroll
      for (int q = 0; q < 4; ++q)
        red[wv][jg][b*4+q] = acc[b][q];
  }
  __syncthreads();
  for (int s = tid; s < 512; s += 256) {
    const int jg2 = s >> 5;
    const int v2  = s & 31;
    const int b   = v2 >> 2, q = v2 & 3;
    const int jo  = j0 + jg2*4 + q;
    const float sum = red[0][jg2][v2] + red[1][jg2][v2]
                    + red[2][jg2][v2] + red[3][jg2][v2];
    const float v = sum + b1[jo];
    h1[(size_t)b*D_ + jo] = 0.5f * v * (1.0f + erff(v * 0.70710678118654752f));
  }
}

// ---------------------------------------------------------------- mlp layer 2 (tanh)
__global__ __launch_bounds__(256) void k_mlp2(
    const float* __restrict__ h1g, const float* __restrict__ h1l,
    const float* __restrict__ w2g, const float* __restrict__ b2g,
    const float* __restrict__ w2l, const float* __restrict__ b2l,
    float* __restrict__ mg, float* __restrict__ ml) {
  __shared__ float hs[B_*D_];
  __shared__ float red[4][16][33];
  const int tid = threadIdx.x;
  const bool isg = (blockIdx.x < 193);
  const float* h1 = isg ? h1g : h1l;
  const float* w2 = isg ? w2g : w2l;
  const float* b2 = isg ? b2g : b2l;
  float*       mo = isg ? mg  : ml;
  const int Jmax = isg ? (H_*GB_) : (H_*LB_);
  const int j0   = isg ? (int)blockIdx.x*64 : ((int)blockIdx.x-193)*64;

  for (int i = tid; i < B_*D_; i += 256) hs[i] = h1[i];
  __syncthreads();

  const int jg    = tid & 15;
  const int slice = tid >> 4;
  const int j     = j0 + jg*4;
  float acc[8][4] = {};
  if (j < Jmax) {
    const float4* w24 = (const float4*)w2;
    const int jc   = j >> 2;
    const int rowq = Jmax >> 2;
    const int i0   = slice*48;
    #pragma unroll 4
    for (int ii = 0; ii < 48; ++ii) {
      const int i = i0 + ii;
      const float4 w = w24[(size_t)i*rowq + jc];
      #pragma unroll
      for (int b = 0; b < 8; ++b) {
        const float hv = hs[b*D_ + i];
        acc[b][0] = fmaf(hv, w.x, acc[b][0]);
        acc[b][1] = fmaf(hv, w.y, acc[b][1]);
        acc[b][2] = fmaf(hv, w.z, acc[b][2]);
        acc[b][3] = fmaf(hv, w.w, acc[b][3]);
      }
    }
  }
  #pragma unroll
  for (int b = 0; b < 8; ++b) {
    #pragma unroll
    for (int q = 0; q < 4; ++q) {
      float v = acc[b][q];
      v += __shfl_xor(v, 16, 64);
      v += __shfl_xor(v, 32, 64);
      acc[b][q] = v;
    }
  }
  const int wv = tid >> 6;
  if ((tid & 63) < 16) {
    #pragma unroll
    for (int b = 0; b < 8; ++b)
      #pragma unroll
      for (int q = 0; q < 4; ++q)
        red[wv][jg][b*4+q] = acc[b][q];
  }
  __syncthreads();
  for (int s = tid; s < 512; s += 256) {
    const int jg2 = s >> 5;
    const int v2  = s & 31;
    const int b   = v2 >> 2, q = v2 & 3;
    const int jo  = j0 + jg2*4 + q;
    if (jo < Jmax) {
      const float sum = red[0][jg2][v2] + red[1][jg2][v2]
                      + red[2][jg2][v2] + red[3][jg2][v2];
      mo[(size_t)b*Jmax + jo] = tanhf(sum + b2[jo]);
    }
  }
}

// ---------------------------------------------------------------- spectral
// One block per COLUMN PAIR (d, d+1). Local windows read packed x straight
// from cb (pre-FFT) and overlap-add via shfl_up into 16 registers — no xc/la
// LDS arrays. LDS ~26 KB -> occupancy bound moves to VGPR (~5 blocks/CU).
__global__ __launch_bounds__(256) void k_spectral(
    const float* __restrict__ x,
    const float* __restrict__ bfg, const float* __restrict__ bfl,
    const float* __restrict__ mbg, const float* __restrict__ mbl,
    const float* __restrict__ mg,  const float* __restrict__ ml,
    const float* __restrict__ fw,  float* __restrict__ fused) {
  __shared__ float2 cb[N_ + (N_>>4)];       // swizzled complex buffer (17.4 KB)
  __shared__ float2 tw[1024];               // tw[m] = exp(-i*pi*m/1024) (8 KB)
  __shared__ float  t1b[4][8], t2b[4][8];   // wave-boundary window tails
  __shared__ float  lf[LB_], lb[LB_];       // local filter / bias (per (b,h))

  const int tid = threadIdx.x;
  const int id  = blockIdx.x;               // 3072
  const int v_  = (id & 7) * 384 + (id >> 3);   // XCD-resident remap
  const int dp  = v_ & 31;
  const int bh  = v_ >> 5;
  const int h   = bh % H_;
  const int b   = bh / H_;
  const int d   = dp * 2;
  const int c   = h*HD_ + d;
  const int col0 = bh*HD_ + d;

  for (int m = tid; m < 1024; m += 256) {
    float s_, c_;
    sincospif(-(float)m * (1.0f/1024.0f), &s_, &c_);
    tw[m] = make_float2(c_, s_);
  }
  if (tid < LB_) {
    lf[tid] = bfl[h*LB_ + tid] + ml[(size_t)b*(H_*LB_) + h*LB_ + tid];
    lb[tid] = mbl[h*LB_ + tid];
  }
  for (int n = tid; n < N_; n += 256) {
    const float2 v = *(const float2*)&x[((size_t)(b*N_ + n))*D_ + c];
    cb[CBX(n)] = v;                          // z = x_d + i*x_{d+1}
  }
  __syncthreads();

  // ---- local windowed path FIRST (cb still holds raw x) ----
  const float HWIN[16] = {0.0f, 0.038060233744356624f, 0.14644660940672624f, 0.30865828381745508f,
                          0.5f, 0.69134171618254492f, 0.85355339059327376f, 0.96193976625564337f,
                          1.0f, 0.96193976625564337f, 0.85355339059327376f, 0.69134171618254492f,
                          0.5f, 0.30865828381745508f, 0.14644660940672624f, 0.038060233744356624f};
  float w1a[16], w2a[16];
  {
    const int j = tid;
    if (j < NW_) {
      float yr[16], yi[16];
      #pragma unroll
      for (int t = 0; t < 16; ++t) {
        const float2 v = cb[CBX(j*8 + t)];
        yr[t] = v.x * HWIN[t];
        yi[t] = v.y * HWIN[t];
      }
      // forward FFT16 (DIF, natural -> bitrev)
      FBF1(0,8); FBF(1,9,C1_,-S1_); FBF(2,10,R2_,-R2_); FBF(3,11,S1_,-C1_);
      FBFmi(4,12); FBF(5,13,-S1_,-C1_); FBF(6,14,-R2_,-R2_); FBF(7,15,-C1_,-S1_);
      FBF1(0,4); FBF(1,5,R2_,-R2_); FBFmi(2,6); FBF(3,7,-R2_,-R2_);
      FBF1(8,12); FBF(9,13,R2_,-R2_); FBFmi(10,14); FBF(11,15,-R2_,-R2_);
      FBF1(0,2); FBFmi(1,3); FBF1(4,6); FBFmi(5,7);
      FBF1(8,10); FBFmi(9,11); FBF1(12,14); FBFmi(13,15);
      FBF1(0,1); FBF1(2,3); FBF1(4,5); FBF1(6,7);
      FBF1(8,9); FBF1(10,11); FBF1(12,13); FBF1(14,15);
      // separate F1/F2 (bitrev), filter+modrelu, repack W (bitrev)
      {
        const int IA[9] = {0,8,4,12,2,10,6,14,1};
        const int IB[9] = {0,15,7,11,3,13,5,9,1};
        #pragma unroll
        for (int l = 0; l <= 8; ++l) {
          const int ia = IA[l], ib = IB[l];
          const float Zar=yr[ia], Zai=yi[ia], Zbr=yr[ib], Zbi=yi[ib];
          float f1r = 0.125f*(Zar+Zbr), f1i = 0.125f*(Zai-Zbi);
          float f2r = 0.125f*(Zai+Zbi), f2i = 0.125f*(Zbr-Zar);
          const float ft = lf[l], bs = lb[l];
          f1r *= ft; f1i *= ft; f2r *= ft; f2i *= ft;
          const float a1 = sqrtf(f1r*f1r + f1i*f1i);
          const float m1 = fmaxf(a1 + bs, 0.0f) / fmaxf(a1, 1e-6f);
          f1r *= m1; f1i *= m1;
          const float a2 = sqrtf(f2r*f2r + f2i*f2i);
          const float m2 = fmaxf(a2 + bs, 0.0f) / fmaxf(a2, 1e-6f);
          f2r *= m2; f2i *= m2;
          yr[ia] = f1r - f2i; yi[ia] = f1i + f2r;
          if (l >= 1 && l <= 7) { yr[ib] = f1r + f2i; yi[ib] = f2r - f1i; }
        }
      }
      // inverse FFT16 (DIT, bitrev -> natural)
      IBF1(0,1); IBF1(2,3); IBF1(4,5); IBF1(6,7);
      IBF1(8,9); IBF1(10,11); IBF1(12,13); IBF1(14,15);
      IBF1(0,2); IBFpi(1,3); IBF1(4,6); IBFpi(5,7);
      IBF1(8,10); IBFpi(9,11); IBF1(12,14); IBFpi(13,15);
      IBF1(0,4); IBF(1,5,R2_,R2_); IBFpi(2,6); IBF(3,7,-R2_,R2_);
      IBF1(8,12); IBF(9,13,R2_,R2_); IBFpi(10,14); IBF(11,15,-R2_,R2_);
      IBF1(0,8); IBF(1,9,C1_,S1_); IBF(2,10,R2_,R2_); IBF(3,11,S1_,C1_);
      IBFpi(4,12); IBF(5,13,-S1_,C1_); IBF(6,14,-R2_,R2_); IBF(7,15,-C1_,S1_);
      #pragma unroll
      for (int t = 0; t < 16; ++t) {
        const float q = 0.25f * HWIN[t];
        w1a[t] = yr[t] * q;
        w2a[t] = yi[t] * q;
      }
    } else {
      #pragma unroll
      for (int t = 0; t < 16; ++t) { w1a[t] = 0.0f; w2a[t] = 0.0f; }
    }
  }
  const int lane = tid & 63, wvi = tid >> 6;
  if (lane == 63 && tid < NW_) {
    #pragma unroll
    for (int s = 0; s < 8; ++s) { t1b[wvi][s] = w1a[8+s]; t2b[wvi][s] = w2a[8+s]; }
  }
  __syncthreads();   // tails visible; local cb reads done before FFT writes

  // overlap-add: sample 8*tid+s = head(window tid) + tail(window tid-1)
  float r1[8], r2[8];
  #pragma unroll
  for (int s = 0; s < 8; ++s) {
    float p1 = __shfl_up(w1a[s+8], 1, 64);
    float p2 = __shfl_up(w2a[s+8], 1, 64);
    if (lane == 0) {
      p1 = wvi ? t1b[wvi-1][s] : 0.0f;
      p2 = wvi ? t2b[wvi-1][s] : 0.0f;
    }
    r1[s] = w1a[s] + p1;
    r2[s] = w2a[s] + p2;
  }

  // ---- forward FFT: radix-2 DIF, stages paired (natural in -> bitrev out) ----
  #pragma unroll
  for (int sh = 10; sh >= 2; sh -= 2) {
    const int hspan = 1 << sh, hh = hspan >> 1;
    for (int t = tid; t < 512; t += 256) {
      const int p  = t & (hh-1);
      const int g  = t >> (sh-1);
      const int i0 = (g << (sh+1)) | p;
      float2 a = cb[CBX(i0)], bb = cb[CBX(i0+hh)], cc = cb[CBX(i0+hspan)], dd = cb[CBX(i0+hspan+hh)];
      const float2 w1  = tw[p << (10-sh)];
      const float2 w1b = tw[(p+hh) << (10-sh)];
      const float2 w2  = tw[p << (11-sh)];
      float2 ap = caddf(a, cc),  cp = cmulf(csubf(a, cc), w1);
      float2 bp = caddf(bb, dd), dp2 = cmulf(csubf(bb, dd), w1b);
      cb[CBX(i0)]          = caddf(ap, bp);
      cb[CBX(i0+hh)]       = cmulf(csubf(ap, bp), w2);
      cb[CBX(i0+hspan)]    = caddf(cp, dp2);
      cb[CBX(i0+hspan+hh)] = cmulf(csubf(cp, dp2), w2);
    }
    __syncthreads();
  }
  for (int t = tid; t < 1024; t += 256) {
    const int i0 = t << 1;
    float2 a = cb[CBX(i0)], bb = cb[CBX(i0+1)];
    cb[CBX(i0)]   = caddf(a, bb);
    cb[CBX(i0+1)] = csubf(a, bb);
  }
  __syncthreads();

  // ---- separate packed spectra, filter+modrelu both, repack (bitrev domain) ----
  const float fsc = 0.022097086912079610f;   // 1/sqrt(2048)
  {
    const float* mgp = mg + (size_t)b*(H_*GB_) + h*GB_;
    const float* bfp = bfg + h*GB_;
    const float* mbp = mbg + h*GB_;
    for (int k = tid; k < 1024; k += 256) {
      if (k == 0) {
        float2 Z0 = cb[CBX(0)], Zn = cb[CBX(1)];
        float g1 = Z0.x * fsc, g2 = Z0.y * fsc;
        {
          const float filt = bfp[0] + mgp[0], bias = mbp[0];
          g1 *= filt; g2 *= filt;
          float a1 = fabsf(g1); g1 *= fmaxf(a1 + bias, 0.0f) / fmaxf(a1, 1e-6f);
          float a2 = fabsf(g2); g2 *= fmaxf(a2 + bias, 0.0f) / fmaxf(a2, 1e-6f);
        }
        cb[CBX(0)] = make_float2(g1, g2);
        float n1 = Zn.x * fsc, n2 = Zn.y * fsc;
        {
          const float filt = bfp[1024] + mgp[1024], bias = mbp[1024];
          n1 *= filt; n2 *= filt;
          float a1 = fabsf(n1); n1 *= fmaxf(a1 + bias, 0.0f) / fmaxf(a1, 1e-6f);
          float a2 = fabsf(n2); n2 *= fmaxf(a2 + bias, 0.0f) / fmaxf(a2, 1e-6f);
        }
        cb[CBX(1)] = make_float2(n1, n2);
      } else {
        const int ik  = (int)(__brev((unsigned)k) >> 21);
        const int imk = (int)(__brev((unsigned)(2048 - k)) >> 21);
        const float2 Za = cb[CBX(ik)], Zb = cb[CBX(imk)];
        const float hs_ = 0.5f * fsc;
        float f1r = (Za.x + Zb.x) * hs_, f1i = (Za.y - Zb.y) * hs_;
        float f2r = (Za.y + Zb.y) * hs_, f2i = (Zb.x - Za.x) * hs_;
        const float filt = bfp[k] + mgp[k], bias = mbp[k];
        f1r *= filt; f1i *= filt; f2r *= filt; f2i *= filt;
        const float a1 = sqrtf(f1r*f1r + f1i*f1i);
        const float s1 = fmaxf(a1 + bias, 0.0f) / fmaxf(a1, 1e-6f);
        f1r *= s1; f1i *= s1;
        const float a2 = sqrtf(f2r*f2r + f2i*f2i);
        const float s2 = fmaxf(a2 + bias, 0.0f) / fmaxf(a2, 1e-6f);
        f2r *= s2; f2i *= s2;
        cb[CBX(ik)]  = make_float2(f1r - f2i, f1i + f2r);
        cb[CBX(imk)] = make_float2(f1r + f2i, f2r - f1i);
      }
    }
  }
  __syncthreads();

  // ---- inverse FFT: radix-2 DIT (bitrev in -> natural out) ----
  for (int t = tid; t < 1024; t += 256) {
    const int i0 = t << 1;
    float2 a = cb[CBX(i0)], bb = cb[CBX(i0+1)];
    cb[CBX(i0)]   = caddf(a, bb);
    cb[CBX(i0+1)] = csubf(a, bb);
  }
  __syncthreads();
  #pragma unroll
  for (int sh = 2; sh <= 10; sh += 2) {
    const int hspan = 1 << sh, hh = hspan >> 1;
    for (int t = tid; t < 512; t += 256) {
      const int p  = t & (hh-1);
      const int g  = t >> (sh-1);
      const int i0 = (g << (sh+1)) | p;
      float2 a = cb[CBX(i0)], bb = cb[CBX(i0+hh)], cc = cb[CBX(i0+hspan)], dd = cb[CBX(i0+hspan+hh)];
      float2 w2  = tw[p << (11-sh)];       w2.y  = -w2.y;
      float2 w1  = tw[p << (10-sh)];       w1.y  = -w1.y;
      float2 w1b = tw[(p+hh) << (10-sh)];  w1b.y = -w1b.y;
      float2 t1 = cmulf(bb, w2);
      float2 ap = caddf(a, t1),  bp = csubf(a, t1);
      float2 t2 = cmulf(dd, w2);
      float2 cp = caddf(cc, t2), dp2 = csubf(cc, t2);
      float2 T = cmulf(cp, w1);
      float2 U = cmulf(dp2, w1b);
      cb[CBX(i0)]          = caddf(ap, T);
      cb[CBX(i0+hspan)]    = csubf(ap, T);
      cb[CBX(i0+hh)]       = caddf(bp, U);
      cb[CBX(i0+hspan+hh)] = csubf(bp, U);
    }
    __syncthreads();
  }

  // ---- fuse + store: thread j owns n in [8j, 8j+8) ----
  const float fw1v = fw[1];
  const float fwg  = fw[0] * fsc;
  float* f0 = fused + (size_t)col0 * N_;
  float* f1p = f0 + N_;
  const int n0 = tid * 8;
  float v0[8], v1[8];
  #pragma unroll
  for (int s = 0; s < 8; ++s) {
    const float2 g = cb[CBX(n0 + s)];
    v0[s] = fwg * g.x + fw1v * r1[s];
    v1[s] = fwg * g.y + fw1v * r2[s];
  }
  *(float4*)&f0[n0]    = make_float4(v0[0], v0[1], v0[2], v0[3]);
  *(float4*)&f0[n0+4]  = make_float4(v0[4], v0[5], v0[6], v0[7]);
  *(float4*)&f1p[n0]   = make_float4(v1[0], v1[1], v1[2], v1[3]);
  *(float4*)&f1p[n0+4] = make_float4(v1[4], v1[5], v1[6], v1[7]);
}

// ---------------------------------------------------------------- residual + LayerNorm
__global__ __launch_bounds__(256) void k_ln(const float* __restrict__ x,
                                            const float* __restrict__ fused,
                                            const float* __restrict__ gamma,
                                            const float* __restrict__ beta,
                                            float* __restrict__ out) {
  __shared__ float yt[16*776];     // stride 776: 776%32==8 -> 2-way max in reduce
  __shared__ float mus[16], rsd[16];
  const int bi = blockIdx.x;
  const int b  = bi >> 7;
  const int n0 = (bi & 127) * 16;
  const int tid = threadIdx.x;

  {
    const float4* x4 = (const float4*)(x + ((size_t)(b*N_ + n0))*D_);
    for (int i = tid; i < 16*D_/4; i += 256) {
      const int nn = i / 192, r = i - nn*192;
      const float4 v = x4[i];
      float* yp = &yt[nn*776 + r*4];
      yp[0] = v.x; yp[1] = v.y; yp[2] = v.z; yp[3] = v.w;
    }
  }
  __syncthreads();
  {
    const float4* fu4 = (const float4*)fused;
    for (int i = tid; i < 16*D_/4; i += 256) {
      const int cc = i >> 2, q = (i & 3) * 4;
      const float4 g = fu4[(((size_t)(b*D_ + cc))*N_ + n0)/4 + (i & 3)];
      yt[(q+0)*776 + cc] += g.x;
      yt[(q+1)*776 + cc] += g.y;
      yt[(q+2)*776 + cc] += g.z;
      yt[(q+3)*776 + cc] += g.w;
    }
  }
  __syncthreads();
  const int nn = tid >> 4, cl = tid & 15;
  float s1 = 0.0f, s2 = 0.0f;
  for (int c = cl; c < D_; c += 16) {
    const float v = yt[nn*776 + c];
    s1 += v; s2 += v*v;
  }
  #pragma unroll
  for (int m = 8; m >= 1; m >>= 1) {
    s1 += __shfl_xor(s1, m, 16);
    s2 += __shfl_xor(s2, m, 16);
  }
  if (cl == 0) {
    const float mu  = s1 * (1.0f/(float)D_);
    const float var = s2 * (1.0f/(float)D_) - mu*mu;
    mus[nn] = mu;
    rsd[nn] = rsqrtf(var + 1e-5f);
  }
  __syncthreads();
  {
    float4* o4 = (float4*)(out + ((size_t)(b*N_ + n0))*D_);
    const float4* g4 = (const float4*)gamma;
    const float4* be4 = (const float4*)beta;
    for (int i = tid; i < 16*D_/4; i += 256) {
      const int nn2 = i / 192, r = i - nn2*192;
      const float mu = mus[nn2], rs = rsd[nn2];
      const float4 gm = g4[r], bt = be4[r];
      const float* yp = &yt[nn2*776 + r*4];
      float4 o;
      o.x = (yp[0] - mu) * rs * gm.x + bt.x;
      o.y = (yp[1] - mu) * rs * gm.y + bt.y;
      o.z = (yp[2] - mu) * rs * gm.z + bt.z;
      o.w = (yp[3] - mu) * rs * gm.w + bt.w;
      o4[i] = o;
    }
  }
}

// ---------------------------------------------------------------- launch
extern "C" void kernel_launch(void* const* d_in, const int* in_sizes, int n_in,
                              void* d_out, int out_size, void* d_ws, size_t ws_size,
                              hipStream_t stream) {
  const float* x   = (const float*)d_in[0];
  const float* bfg = (const float*)d_in[1];
  const float* bfl = (const float*)d_in[2];
  const float* mbg = (const float*)d_in[3];
  const float* mbl = (const float*)d_in[4];
  const float* w1g = (const float*)d_in[5];
  const float* b1g = (const float*)d_in[6];
  const float* w2g = (const float*)d_in[7];
  const float* b2g = (const float*)d_in[8];
  const float* w1l = (const float*)d_in[9];
  const float* b1l = (const float*)d_in[10];
  const float* w2l = (const float*)d_in[11];
  const float* b2l = (const float*)d_in[12];
  const float* fw  = (const float*)d_in[13];
  const float* gam = (const float*)d_in[14];
  const float* bet = (const float*)d_in[15];
  float* out = (float*)d_out;

  float* ws    = (float*)d_ws;
  float* ctx   = ws;                 // 6144
  float* h1g   = ws + 6144;
  float* h1l   = ws + 12288;
  float* mg    = ws + 18432;         // 98400
  float* ml    = ws + 116832;        // 864
  float* fused = ws + 117696;        // 8*768*2048

  hipMemsetAsync(ctx, 0, (size_t)B_*D_*sizeof(float), stream);
  k_ctx<<<dim3(B_, 32), 256, 0, stream>>>(x, ctx);
  k_mlp1<<<dim3(12, 2), 256, 0, stream>>>(ctx, w1g, b1g, w1l, b1l, h1g, h1l);
  k_mlp2<<<195, 256, 0, stream>>>(h1g, h1l, w2g, b2g, w2l, b2l, mg, ml);
  k_spectral<<<B_*H_*32, 256, 0, stream>>>(x, bfg, bfl, mbg, mbl, mg, ml, fw, fused);
  k_ln<<<B_*N_/16, 256, 0, stream>>>(x, fused, gam, bet, out);
}